// Round 1
// baseline (552.150 us; speedup 1.0000x reference)
//
#include <hip/hip_runtime.h>
#include <stdint.h>

// Problem constants (LTXSelfAttention: B=2, S=2048, D=2048, H=32, DH=64)
#define BD 2
#define SD 2048
#define DD 2048
#define HD 32
#define DH 64
#define MD (BD*SD)   // 4096 rows

typedef __attribute__((ext_vector_type(8))) short short8;
typedef __attribute__((ext_vector_type(8))) __bf16 bf16x8;
typedef __attribute__((ext_vector_type(4))) float f32x4;
typedef unsigned short u16;
typedef unsigned int u32;

__device__ __forceinline__ u16 f2bf(float f) {
    u32 u = __float_as_uint(f);
    u32 r = (u + 0x7fffu + ((u >> 16) & 1u)) >> 16;   // RNE
    return (u16)r;
}
__device__ __forceinline__ float bf2f(u16 h) {
    return __uint_as_float(((u32)h) << 16);
}
// gfx950 MFMA 16x16x32 bf16. LLVM signature takes v8bf16; we load as short8 and bit_cast.
__device__ __forceinline__ f32x4 mfma16(short8 a, short8 b, f32x4 c) {
    return __builtin_amdgcn_mfma_f32_16x16x32_bf16(
        __builtin_bit_cast(bf16x8, a), __builtin_bit_cast(bf16x8, b), c, 0, 0, 0);
}
// async global->LDS, 16B per lane (wave-uniform LDS base + lane*16 — layout kept linear)
__device__ __forceinline__ void gload16(const void* g, void* l) {
    __builtin_amdgcn_global_load_lds(
        (const __attribute__((address_space(1))) u32*)g,
        (__attribute__((address_space(3))) u32*)l, 16, 0, 0);
}

// ---------------- fp32 -> bf16 convert ----------------
__global__ __launch_bounds__(256) void cvt_f32_bf16(const float* __restrict__ s,
                                                    u16* __restrict__ d, int n4) {
    int i = blockIdx.x * 256 + threadIdx.x;
    if (i >= n4) return;
    float4 v = reinterpret_cast<const float4*>(s)[i];
    u32 lo = (u32)f2bf(v.x) | ((u32)f2bf(v.y) << 16);
    u32 hi = (u32)f2bf(v.z) | ((u32)f2bf(v.w) << 16);
    reinterpret_cast<uint2*>(d)[i] = make_uint2(lo, hi);
}

// ---------------- GEMM: C[M,N] = A[M,K] * B[N,K]^T + bias (NT, bf16 in, fp32 acc) ----
// 128x128 tile, BK=64, 256 threads (4 waves, 2x2 wave grid, 64x64 per wave).
// m97 structure: global_load_lds width-16 staging + 2 K-steps of 16 MFMA.
#define BM 128
#define BN 128
#define BK 64

template<int OUTF32>
__global__ __launch_bounds__(256) void gemm_nt(
    const u16* __restrict__ A,
    const u16* __restrict__ B0, const u16* __restrict__ B1, const u16* __restrict__ B2,
    const float* __restrict__ c0, const float* __restrict__ c1, const float* __restrict__ c2,
    void* __restrict__ o0, void* __restrict__ o1, void* __restrict__ o2,
    int M, int N, int K)
{
    __shared__ __align__(16) u16 Asm[BM * BK];
    __shared__ __align__(16) u16 Bsm[BN * BK];
    const int z = blockIdx.z;
    const u16* Bm = z == 0 ? B0 : (z == 1 ? B1 : B2);
    const float* bias = z == 0 ? c0 : (z == 1 ? c1 : c2);
    void* outp = z == 0 ? o0 : (z == 1 ? o1 : o2);

    const int tid = threadIdx.x;
    const int m0 = blockIdx.y * BM;
    const int n0 = blockIdx.x * BN;
    const int lane = tid & 63;
    const int w = tid >> 6;
    const int wm = (w >> 1) * 64, wn = (w & 1) * 64;
    const int lr = lane & 15, lg = lane >> 4;

    // staging addresses: chunk c = tid + i*256 covers row c>>3, cols (c&7)*8 (16B)
    const u16* aSrc = A + (size_t)(m0 + (tid >> 3)) * K + (tid & 7) * 8;
    const u16* bSrc = Bm + (size_t)(n0 + (tid >> 3)) * K + (tid & 7) * 8;
    u16* aDst = &Asm[tid * 8];
    u16* bDst = &Bsm[tid * 8];

    f32x4 acc[4][4];
#pragma unroll
    for (int i = 0; i < 4; ++i)
#pragma unroll
        for (int j = 0; j < 4; ++j) acc[i][j] = (f32x4){0.f, 0.f, 0.f, 0.f};

    for (int kt = 0; kt < K; kt += BK) {
        __syncthreads();   // previous compute done before overwriting LDS
#pragma unroll
        for (int i = 0; i < 4; ++i) gload16(aSrc + (size_t)i * 32 * K + kt, aDst + i * 2048);
#pragma unroll
        for (int i = 0; i < 4; ++i) gload16(bSrc + (size_t)i * 32 * K + kt, bDst + i * 2048);
        asm volatile("s_waitcnt vmcnt(0)" ::: "memory");
        __syncthreads();
#pragma unroll
        for (int s = 0; s < 2; ++s) {
            const int kc = s * 32 + lg * 8;
            short8 av[4], bv[4];
#pragma unroll
            for (int i = 0; i < 4; ++i) av[i] = *(const short8*)&Asm[(wm + i * 16 + lr) * BK + kc];
#pragma unroll
            for (int j = 0; j < 4; ++j) bv[j] = *(const short8*)&Bsm[(wn + j * 16 + lr) * BK + kc];
#pragma unroll
            for (int i = 0; i < 4; ++i)
#pragma unroll
                for (int j = 0; j < 4; ++j) acc[i][j] = mfma16(av[i], bv[j], acc[i][j]);
        }
    }
    // epilogue: C/D layout col = lane&15, row = (lane>>4)*4 + reg
#pragma unroll
    for (int j = 0; j < 4; ++j) {
        const int col = n0 + wn + j * 16 + lr;
        const float bj = bias[col];
#pragma unroll
        for (int i = 0; i < 4; ++i) {
            const int row = m0 + wm + i * 16 + lg * 4;
#pragma unroll
            for (int r = 0; r < 4; ++r) {
                float v = acc[i][j][r] + bj;
                if (OUTF32) ((float*)outp)[(size_t)(row + r) * N + col] = v;
                else        ((u16*)outp)[(size_t)(row + r) * N + col] = f2bf(v);
            }
        }
    }
}

// ---------------- fused RMSNorm (over D=2048) + interleaved RoPE, in-place bf16 ------
// grid.y==0 -> q (also folds in softmax scale 1/8, exact), grid.y==1 -> k
__global__ __launch_bounds__(256) void rmsnorm_rope(
    u16* __restrict__ q, u16* __restrict__ k,
    const float* __restrict__ qw, const float* __restrict__ kw,
    const float* __restrict__ pc, const float* __restrict__ ps)
{
    const int row = blockIdx.x;           // 0..MD-1 (b*S + s)
    const int s = row & (SD - 1);
    const bool isq = (blockIdx.y == 0);
    u16* t = isq ? q : k;
    const float* w = isq ? qw : kw;
    const float outscale = isq ? 0.125f : 1.0f;   // 1/sqrt(DH)=0.125 folded into q

    const int off = threadIdx.x * 8;
    u16* rp = t + (size_t)row * DD + off;
    short8 raw = *(const short8*)rp;
    float v[8]; float ss = 0.f;
#pragma unroll
    for (int j = 0; j < 8; ++j) { v[j] = bf2f((u16)raw[j]); ss += v[j] * v[j]; }
#pragma unroll
    for (int m = 1; m < 64; m <<= 1) ss += __shfl_xor(ss, m, 64);
    __shared__ float red[4];
    if ((threadIdx.x & 63) == 0) red[threadIdx.x >> 6] = ss;
    __syncthreads();
    const float tot = red[0] + red[1] + red[2] + red[3];
    const float rms = rsqrtf(tot * (1.0f / DD) + 1e-6f);

    float wv[8], cv[8], sv[8];
    *(float4*)&wv[0] = *(const float4*)(w + off);
    *(float4*)&wv[4] = *(const float4*)(w + off + 4);
    *(float4*)&cv[0] = *(const float4*)(pc + (size_t)s * DD + off);
    *(float4*)&cv[4] = *(const float4*)(pc + (size_t)s * DD + off + 4);
    *(float4*)&sv[0] = *(const float4*)(ps + (size_t)s * DD + off);
    *(float4*)&sv[4] = *(const float4*)(ps + (size_t)s * DD + off + 4);

    short8 outb;
#pragma unroll
    for (int u = 0; u < 4; ++u) {
        float e  = v[2 * u]     * rms * wv[2 * u];
        float od = v[2 * u + 1] * rms * wv[2 * u + 1];
        float r0 = e * cv[2 * u]      - od * sv[2 * u];
        float r1 = od * cv[2 * u + 1] + e  * sv[2 * u + 1];
        outb[2 * u]     = (short)f2bf(r0 * outscale);
        outb[2 * u + 1] = (short)f2bf(r1 * outscale);
    }
    *(short8*)rp = outb;
}

// ---------------- flash attention, bf16 MFMA ----------------
// block = 256 thr (4 waves), grid = (S/64, B*H). Each wave: 16 q-rows x DH=64.
// KV tile = 64. K row-major in LDS (pad 80 to cut b128 read conflicts to ~4-way),
// V transposed in LDS (Vt[d][k]) so PV B-frags are contiguous, P via LDS round-trip.
#define KPAD 80

__global__ __launch_bounds__(256) void attn_fwd(
    const u16* __restrict__ qb, const u16* __restrict__ kb,
    const u16* __restrict__ vb, u16* __restrict__ ob)
{
    __shared__ __align__(16) u16 Ksm[64 * KPAD];
    __shared__ __align__(16) u16 Vsm[64 * KPAD];   // Vt[d][k]
    __shared__ __align__(16) u16 Psm[64 * KPAD];   // wave w owns rows w*16..w*16+15
    const int bh = blockIdx.y;
    const int b = bh >> 5, h = bh & 31;
    const int q0 = blockIdx.x * 64;
    const int tid = threadIdx.x;
    const int w = tid >> 6, lane = tid & 63;
    const int lr = lane & 15, lg = lane >> 4;

    const size_t headoff = (size_t)b * SD * DD + (size_t)h * DH;
    // Q fragments (A-operand: row = lane&15, k = (lane>>4)*8 + j), held all kernel
    const u16* qrow = qb + headoff + (size_t)(q0 + w * 16 + lr) * DD + lg * 8;
    const short8 qf0 = *(const short8*)qrow;
    const short8 qf1 = *(const short8*)(qrow + 32);

    f32x4 o[4];
#pragma unroll
    for (int dt = 0; dt < 4; ++dt) o[dt] = (f32x4){0.f, 0.f, 0.f, 0.f};
    float mrow[4] = {-1e30f, -1e30f, -1e30f, -1e30f};
    float lsum[4] = {0.f, 0.f, 0.f, 0.f};

    const u16* kbase = kb + headoff;
    const u16* vbase = vb + headoff;

    for (int kv = 0; kv < SD; kv += 64) {
        __syncthreads();
        // stage K (row-major) and V (transposed): 512 chunks of 8 bf16
#pragma unroll
        for (int i = 0; i < 2; ++i) {
            const int c = tid + i * 256;
            const int r = c >> 3, cc = (c & 7) * 8;
            short8 kk = *(const short8*)(kbase + (size_t)(kv + r) * DD + cc);
            *(short8*)&Ksm[r * KPAD + cc] = kk;
            short8 vv = *(const short8*)(vbase + (size_t)(kv + r) * DD + cc);
#pragma unroll
            for (int j = 0; j < 8; ++j) Vsm[(cc + j) * KPAD + r] = (u16)vv[j];
        }
        __syncthreads();

        // scores: S[16q x 16k] per kt, reduce over d (2 MFMA of K=32)
        f32x4 st[4];
#pragma unroll
        for (int kt = 0; kt < 4; ++kt) {
            short8 kf0 = *(const short8*)&Ksm[(kt * 16 + lr) * KPAD + lg * 8];
            short8 kf1 = *(const short8*)&Ksm[(kt * 16 + lr) * KPAD + 32 + lg * 8];
            f32x4 zz = (f32x4){0.f, 0.f, 0.f, 0.f};
            zz = mfma16(qf0, kf0, zz);
            zz = mfma16(qf1, kf1, zz);
            st[kt] = zz;   // row(q) = lg*4+r, col(key) = kt*16+lr; scale pre-folded in q
        }
        // online softmax (rows live in 16-lane groups; reduce over lr via shfl_xor)
        float mx[4], rs[4];
#pragma unroll
        for (int r = 0; r < 4; ++r)
            mx[r] = fmaxf(fmaxf(st[0][r], st[1][r]), fmaxf(st[2][r], st[3][r]));
#pragma unroll
        for (int offl = 1; offl < 16; offl <<= 1)
#pragma unroll
            for (int r = 0; r < 4; ++r) mx[r] = fmaxf(mx[r], __shfl_xor(mx[r], offl, 64));
        float fac[4];
#pragma unroll
        for (int r = 0; r < 4; ++r) {
            float nm = fmaxf(mrow[r], mx[r]);
            fac[r] = __expf(mrow[r] - nm);
            mrow[r] = nm;
            rs[r] = 0.f;
        }
#pragma unroll
        for (int kt = 0; kt < 4; ++kt) {
#pragma unroll
            for (int r = 0; r < 4; ++r) {
                float p = __expf(st[kt][r] - mrow[r]);
                rs[r] += p;
                Psm[(w * 16 + lg * 4 + r) * KPAD + kt * 16 + lr] = f2bf(p);
            }
        }
#pragma unroll
        for (int offl = 1; offl < 16; offl <<= 1)
#pragma unroll
            for (int r = 0; r < 4; ++r) rs[r] += __shfl_xor(rs[r], offl, 64);
#pragma unroll
        for (int r = 0; r < 4; ++r) lsum[r] = lsum[r] * fac[r] + rs[r];
#pragma unroll
        for (int dt = 0; dt < 4; ++dt)
#pragma unroll
            for (int r = 0; r < 4; ++r) o[dt][r] *= fac[r];

        // PV: A = P (row=q=lr, k=key), B = Vt (n=d=lr, k=key)
#pragma unroll
        for (int ks = 0; ks < 2; ++ks) {
            short8 pa = *(const short8*)&Psm[(w * 16 + lr) * KPAD + ks * 32 + lg * 8];
#pragma unroll
            for (int dt = 0; dt < 4; ++dt) {
                short8 vf = *(const short8*)&Vsm[(dt * 16 + lr) * KPAD + ks * 32 + lg * 8];
                o[dt] = mfma16(pa, vf, o[dt]);
            }
        }
    }
    // write: row(q) = lg*4+r, col(d) = dt*16+lr
#pragma unroll
    for (int dt = 0; dt < 4; ++dt) {
#pragma unroll
        for (int r = 0; r < 4; ++r) {
            const int srow = q0 + w * 16 + lg * 4 + r;
            ob[headoff + (size_t)srow * DD + dt * 16 + lr] = f2bf(o[dt][r] / lsum[r]);
        }
    }
}

// ---------------- launch ----------------
extern "C" void kernel_launch(void* const* d_in, const int* in_sizes, int n_in,
                              void* d_out, int out_size, void* d_ws, size_t ws_size,
                              hipStream_t stream)
{
    (void)in_sizes; (void)n_in; (void)out_size; (void)ws_size;
    const float* x  = (const float*)d_in[0];
    const float* pc = (const float*)d_in[1];
    const float* ps = (const float*)d_in[2];
    const float* Wq = (const float*)d_in[3];
    const float* bq = (const float*)d_in[4];
    const float* Wk = (const float*)d_in[5];
    const float* bk = (const float*)d_in[6];
    const float* Wv = (const float*)d_in[7];
    const float* bv = (const float*)d_in[8];
    const float* qw = (const float*)d_in[9];
    const float* kw = (const float*)d_in[10];
    const float* Wo = (const float*)d_in[11];
    const float* bo = (const float*)d_in[12];
    float* out = (float*)d_out;

    const size_t MDsz = (size_t)MD * DD;   // 8,388,608 elems
    const size_t DDsz = (size_t)DD * DD;   // 4,194,304 elems
    // workspace layout (bf16 = u16). attn output aliases xb (xb dead after QKV GEMM).
    u16* xb   = (u16*)d_ws;
    u16* wqb  = xb  + MDsz;
    u16* wkb  = wqb + DDsz;
    u16* wvb  = wkb + DDsz;
    u16* wob  = wvb + DDsz;
    u16* qbuf = wob + DDsz;
    u16* kbuf = qbuf + MDsz;
    u16* vbuf = kbuf + MDsz;
    u16* aob  = xb;          // reuse: attention output
    // total ws: (4*MDsz + 4*DDsz)*2 B = 100.7 MB

    const int n4m = (int)(MDsz / 4), n4d = (int)(DDsz / 4);
    cvt_f32_bf16<<<dim3((n4m + 255) / 256), 256, 0, stream>>>(x,  xb,  n4m);
    cvt_f32_bf16<<<dim3((n4d + 255) / 256), 256, 0, stream>>>(Wq, wqb, n4d);
    cvt_f32_bf16<<<dim3((n4d + 255) / 256), 256, 0, stream>>>(Wk, wkb, n4d);
    cvt_f32_bf16<<<dim3((n4d + 255) / 256), 256, 0, stream>>>(Wv, wvb, n4d);
    cvt_f32_bf16<<<dim3((n4d + 255) / 256), 256, 0, stream>>>(Wo, wob, n4d);

    // QKV projections fused over grid.z
    gemm_nt<0><<<dim3(DD / BN, MD / BM, 3), 256, 0, stream>>>(
        xb, wqb, wkb, wvb, bq, bk, bv,
        (void*)qbuf, (void*)kbuf, (void*)vbuf, MD, DD, DD);

    rmsnorm_rope<<<dim3(MD, 2), 256, 0, stream>>>(qbuf, kbuf, qw, kw, pc, ps);

    attn_fwd<<<dim3(SD / 64, BD * HD), 256, 0, stream>>>(qbuf, kbuf, vbuf, aob);

    gemm_nt<1><<<dim3(DD / BN, MD / BM, 1), 256, 0, stream>>>(
        aob, wob, wob, wob, bo, bo, bo,
        (void*)out, (void*)out, (void*)out, MD, DD, DD);
}

// Round 2
// 463.719 us; speedup vs baseline: 1.1907x; 1.1907x over previous
//
#include <hip/hip_runtime.h>
#include <stdint.h>

// Problem constants (LTXSelfAttention: B=2, S=2048, D=2048, H=32, DH=64)
#define BD 2
#define SD 2048
#define DD 2048
#define HD 32
#define DH 64
#define MD (BD*SD)   // 4096 rows

typedef __attribute__((ext_vector_type(8))) short short8;
typedef __attribute__((ext_vector_type(8))) __bf16 bf16x8;
typedef __attribute__((ext_vector_type(4))) float f32x4;
typedef unsigned short u16;
typedef unsigned int u32;

__device__ __forceinline__ u16 f2bf(float f) {
    u32 u = __float_as_uint(f);
    u32 r = (u + 0x7fffu + ((u >> 16) & 1u)) >> 16;   // RNE
    return (u16)r;
}
__device__ __forceinline__ float bf2f(u16 h) {
    return __uint_as_float(((u32)h) << 16);
}
__device__ __forceinline__ f32x4 mfma16(short8 a, short8 b, f32x4 c) {
    return __builtin_amdgcn_mfma_f32_16x16x32_bf16(
        __builtin_bit_cast(bf16x8, a), __builtin_bit_cast(bf16x8, b), c, 0, 0, 0);
}
// async global->LDS, 16B per lane (wave-uniform LDS base + lane*16, linear dest)
__device__ __forceinline__ void gload16(const void* g, void* l) {
    __builtin_amdgcn_global_load_lds(
        (const __attribute__((address_space(1))) u32*)g,
        (__attribute__((address_space(3))) u32*)l, 16, 0, 0);
}

// ---------------- fp32 -> bf16 convert ----------------
__global__ __launch_bounds__(256) void cvt_f32_bf16(const float* __restrict__ s,
                                                    u16* __restrict__ d, int n4) {
    int i = blockIdx.x * 256 + threadIdx.x;
    if (i >= n4) return;
    float4 v = reinterpret_cast<const float4*>(s)[i];
    u32 lo = (u32)f2bf(v.x) | ((u32)f2bf(v.y) << 16);
    u32 hi = (u32)f2bf(v.z) | ((u32)f2bf(v.w) << 16);
    reinterpret_cast<uint2*>(d)[i] = make_uint2(lo, hi);
}
// 4 weight matrices in one launch (grid.y selects)
__global__ __launch_bounds__(256) void cvt_w4(
    const float* __restrict__ s0, const float* __restrict__ s1,
    const float* __restrict__ s2, const float* __restrict__ s3,
    u16* __restrict__ d0, u16* __restrict__ d1, u16* __restrict__ d2, u16* __restrict__ d3,
    int n4) {
    int i = blockIdx.x * 256 + threadIdx.x;
    if (i >= n4) return;
    int z = blockIdx.y;
    const float* s = z == 0 ? s0 : z == 1 ? s1 : z == 2 ? s2 : s3;
    u16* d = z == 0 ? d0 : z == 1 ? d1 : z == 2 ? d2 : d3;
    float4 v = reinterpret_cast<const float4*>(s)[i];
    u32 lo = (u32)f2bf(v.x) | ((u32)f2bf(v.y) << 16);
    u32 hi = (u32)f2bf(v.z) | ((u32)f2bf(v.w) << 16);
    reinterpret_cast<uint2*>(d)[i] = make_uint2(lo, hi);
}

// ---------------- GEMM: C[M,N] = A[M,K] * B[N,K]^T + bias (NT, bf16 in, fp32 acc) ----
#define BM 128
#define BN 128
#define BK 64

template<int OUTF32>
__global__ __launch_bounds__(256) void gemm_nt(
    const u16* __restrict__ A,
    const u16* __restrict__ B0, const u16* __restrict__ B1, const u16* __restrict__ B2,
    const float* __restrict__ c0, const float* __restrict__ c1, const float* __restrict__ c2,
    void* __restrict__ o0, void* __restrict__ o1, void* __restrict__ o2,
    int M, int N, int K)
{
    __shared__ __align__(16) u16 Asm[BM * BK];
    __shared__ __align__(16) u16 Bsm[BN * BK];
    const int z = blockIdx.z;
    const u16* Bm = z == 0 ? B0 : (z == 1 ? B1 : B2);
    const float* bias = z == 0 ? c0 : (z == 1 ? c1 : c2);
    void* outp = z == 0 ? o0 : (z == 1 ? o1 : o2);

    const int tid = threadIdx.x;
    const int m0 = blockIdx.y * BM;
    const int n0 = blockIdx.x * BN;
    const int lane = tid & 63;
    const int w = tid >> 6;
    const int wm = (w >> 1) * 64, wn = (w & 1) * 64;
    const int lr = lane & 15, lg = lane >> 4;

    const u16* aSrc = A + (size_t)(m0 + (tid >> 3)) * K + (tid & 7) * 8;
    const u16* bSrc = Bm + (size_t)(n0 + (tid >> 3)) * K + (tid & 7) * 8;
    u16* aDst = &Asm[tid * 8];
    u16* bDst = &Bsm[tid * 8];

    f32x4 acc[4][4];
#pragma unroll
    for (int i = 0; i < 4; ++i)
#pragma unroll
        for (int j = 0; j < 4; ++j) acc[i][j] = (f32x4){0.f, 0.f, 0.f, 0.f};

    for (int kt = 0; kt < K; kt += BK) {
        __syncthreads();
#pragma unroll
        for (int i = 0; i < 4; ++i) gload16(aSrc + (size_t)i * 32 * K + kt, aDst + i * 2048);
#pragma unroll
        for (int i = 0; i < 4; ++i) gload16(bSrc + (size_t)i * 32 * K + kt, bDst + i * 2048);
        asm volatile("s_waitcnt vmcnt(0)" ::: "memory");
        __syncthreads();
#pragma unroll
        for (int s = 0; s < 2; ++s) {
            const int kc = s * 32 + lg * 8;
            short8 av[4], bv[4];
#pragma unroll
            for (int i = 0; i < 4; ++i) av[i] = *(const short8*)&Asm[(wm + i * 16 + lr) * BK + kc];
#pragma unroll
            for (int j = 0; j < 4; ++j) bv[j] = *(const short8*)&Bsm[(wn + j * 16 + lr) * BK + kc];
#pragma unroll
            for (int i = 0; i < 4; ++i)
#pragma unroll
                for (int j = 0; j < 4; ++j) acc[i][j] = mfma16(av[i], bv[j], acc[i][j]);
        }
    }
#pragma unroll
    for (int j = 0; j < 4; ++j) {
        const int col = n0 + wn + j * 16 + lr;
        const float bj = bias[col];
#pragma unroll
        for (int i = 0; i < 4; ++i) {
            const int row = m0 + wm + i * 16 + lg * 4;
#pragma unroll
            for (int r = 0; r < 4; ++r) {
                float v = acc[i][j][r] + bj;
                if (OUTF32) ((float*)outp)[(size_t)(row + r) * N + col] = v;
                else        ((u16*)outp)[(size_t)(row + r) * N + col] = f2bf(v);
            }
        }
    }
}

// ---------------- fused RMSNorm + interleaved RoPE (q AND k per block) ------
__global__ __launch_bounds__(256) void rmsnorm_rope(
    u16* __restrict__ q, u16* __restrict__ k,
    const float* __restrict__ qw, const float* __restrict__ kw,
    const float* __restrict__ pc, const float* __restrict__ ps)
{
    const int row = blockIdx.x;           // 0..MD-1
    const int s = row & (SD - 1);
    const int off = threadIdx.x * 8;
    u16* qp = q + (size_t)row * DD + off;
    u16* kp = k + (size_t)row * DD + off;
    short8 qraw = *(const short8*)qp;
    short8 kraw = *(const short8*)kp;
    float vq[8], vk[8];
    float sq = 0.f, sk = 0.f;
#pragma unroll
    for (int j = 0; j < 8; ++j) {
        vq[j] = bf2f((u16)qraw[j]); sq += vq[j] * vq[j];
        vk[j] = bf2f((u16)kraw[j]); sk += vk[j] * vk[j];
    }
#pragma unroll
    for (int m = 1; m < 64; m <<= 1) { sq += __shfl_xor(sq, m, 64); sk += __shfl_xor(sk, m, 64); }
    __shared__ float redq[4], redk[4];
    const int w = threadIdx.x >> 6;
    if ((threadIdx.x & 63) == 0) { redq[w] = sq; redk[w] = sk; }
    __syncthreads();
    const float rq = rsqrtf((redq[0] + redq[1] + redq[2] + redq[3]) * (1.0f / DD) + 1e-6f);
    const float rk = rsqrtf((redk[0] + redk[1] + redk[2] + redk[3]) * (1.0f / DD) + 1e-6f);

    float wq[8], wk8[8], cv[8], sv[8];
    *(float4*)&wq[0]  = *(const float4*)(qw + off);
    *(float4*)&wq[4]  = *(const float4*)(qw + off + 4);
    *(float4*)&wk8[0] = *(const float4*)(kw + off);
    *(float4*)&wk8[4] = *(const float4*)(kw + off + 4);
    *(float4*)&cv[0] = *(const float4*)(pc + (size_t)s * DD + off);
    *(float4*)&cv[4] = *(const float4*)(pc + (size_t)s * DD + off + 4);
    *(float4*)&sv[0] = *(const float4*)(ps + (size_t)s * DD + off);
    *(float4*)&sv[4] = *(const float4*)(ps + (size_t)s * DD + off + 4);

    short8 qo, ko;
#pragma unroll
    for (int u = 0; u < 4; ++u) {
        float e  = vq[2 * u]     * rq * wq[2 * u];
        float od = vq[2 * u + 1] * rq * wq[2 * u + 1];
        qo[2 * u]     = (short)f2bf((e * cv[2 * u]      - od * sv[2 * u])     * 0.125f);
        qo[2 * u + 1] = (short)f2bf((od * cv[2 * u + 1] + e  * sv[2 * u + 1]) * 0.125f);
        e  = vk[2 * u]     * rk * wk8[2 * u];
        od = vk[2 * u + 1] * rk * wk8[2 * u + 1];
        ko[2 * u]     = (short)f2bf(e * cv[2 * u]      - od * sv[2 * u]);
        ko[2 * u + 1] = (short)f2bf(od * cv[2 * u + 1] + e  * sv[2 * u + 1]);
    }
    *(short8*)qp = qo;
    *(short8*)kp = ko;
}

// ---------------- V transpose: V[b,s,h*64+d] -> Vt[(b*32+h)*64+d][s] ----------------
__global__ __launch_bounds__(256) void transpose_v(
    const u16* __restrict__ v, u16* __restrict__ vt)
{
    __shared__ __align__(16) u16 t[64][80];
    const int bh = blockIdx.y;
    const int b = bh >> 5, h = bh & 31;
    const int s0 = blockIdx.x * 64;
    const int tid = threadIdx.x;
    const u16* src = v + (size_t)b * SD * DD + (size_t)h * DH;
#pragma unroll
    for (int i = 0; i < 2; ++i) {
        int c = tid + i * 256;
        int s = c >> 3, d8 = (c & 7) * 8;
        *(short8*)&t[s][d8] = *(const short8*)(src + (size_t)(s0 + s) * DD + d8);
    }
    __syncthreads();
    u16* dst = vt + (size_t)bh * DH * SD;
#pragma unroll
    for (int i = 0; i < 2; ++i) {
        int c = tid + i * 256;
        int d = c >> 3, s8 = (c & 7) * 8;
        short8 o;
#pragma unroll
        for (int j = 0; j < 8; ++j) o[j] = t[s8 + j][d];
        *(short8*)(dst + (size_t)d * SD + s0 + s8) = o;
    }
}

// ---------------- flash attention ----------------
// block = 256 thr (4 waves), grid = (S/64, B*H). Wave: 16 q-rows x DH=64, KV tile 64.
// K and Vt staged via global_load_lds into [64][64] u16 tiles, XOR-swizzled content
// (pre-swizzled GLOBAL source + swizzled ds_read), double-buffered (2-phase pipeline).
#define PP 80

__device__ __forceinline__ short8 swzread(const u16* base, int row, int colbyte) {
    return *(const short8*)((const char*)base + row * 128 + (colbyte ^ ((row & 7) << 4)));
}

__global__ __launch_bounds__(256) void attn_fwd(
    const u16* __restrict__ qb, const u16* __restrict__ kb,
    const u16* __restrict__ vt, u16* __restrict__ ob)
{
    __shared__ __align__(16) u16 Ksm[2][64 * 64];
    __shared__ __align__(16) u16 Vsm[2][64 * 64];
    __shared__ __align__(16) u16 Psm[64 * PP];
    const int bh = blockIdx.y;
    const int b = bh >> 5;
    const int q0 = blockIdx.x * 64;
    const int tid = threadIdx.x;
    const int w = tid >> 6, lane = tid & 63;
    const int lr = lane & 15, lg = lane >> 4;

    const size_t headoff = (size_t)b * SD * DD + (size_t)(bh & 31) * DH;
    const u16* kbase = kb + headoff;
    const u16* vtbase = vt + (size_t)bh * DH * SD;

    // Q fragments (A-operand: row = lane&15, k = (lane>>4)*8 + j)
    const u16* qrow = qb + headoff + (size_t)(q0 + w * 16 + lr) * DD + lg * 8;
    const short8 qf0 = *(const short8*)qrow;
    const short8 qf1 = *(const short8*)(qrow + 32);

    // staging chunks: c = tid + 256*i; row rr = c>>3, swizzled col16 cc = (c&7)^(rr&7)
    const int rr0 = tid >> 3, cc0 = (tid & 7) ^ (rr0 & 7);
    const int rr1 = (tid + 256) >> 3, cc1 = ((tid + 256) & 7) ^ (rr1 & 7);

    f32x4 o[4];
#pragma unroll
    for (int dt = 0; dt < 4; ++dt) o[dt] = (f32x4){0.f, 0.f, 0.f, 0.f};
    float mrow[4] = {-1e30f, -1e30f, -1e30f, -1e30f};
    float lsum[4] = {0.f, 0.f, 0.f, 0.f};

#define STAGE(buf, kv)                                                              \
    do {                                                                            \
        gload16(kbase + (size_t)((kv) + rr0) * DD + cc0 * 8, &Ksm[buf][tid * 8]);   \
        gload16(kbase + (size_t)((kv) + rr1) * DD + cc1 * 8, &Ksm[buf][tid * 8 + 2048]); \
        gload16(vtbase + (size_t)rr0 * SD + (kv) + cc0 * 8, &Vsm[buf][tid * 8]);    \
        gload16(vtbase + (size_t)rr1 * SD + (kv) + cc1 * 8, &Vsm[buf][tid * 8 + 2048]); \
    } while (0)

    STAGE(0, 0);
    asm volatile("s_waitcnt vmcnt(0)" ::: "memory");
    __syncthreads();

    for (int t = 0; t < SD / 64; ++t) {
        const int cur = t & 1;
        if (t + 1 < SD / 64) STAGE(cur ^ 1, (t + 1) * 64);

        const u16* Kc = Ksm[cur];
        const u16* Vc = Vsm[cur];

        // scores
        f32x4 st[4];
        __builtin_amdgcn_s_setprio(1);
#pragma unroll
        for (int kt = 0; kt < 4; ++kt) {
            const int row = kt * 16 + lr;
            short8 kf0 = swzread(Kc, row, lg * 16);
            short8 kf1 = swzread(Kc, row, 64 + lg * 16);
            f32x4 zz = (f32x4){0.f, 0.f, 0.f, 0.f};
            zz = mfma16(qf0, kf0, zz);
            zz = mfma16(qf1, kf1, zz);
            st[kt] = zz;   // row(q)=lg*4+r, col(key)=kt*16+lr
        }
        __builtin_amdgcn_s_setprio(0);

        // online softmax
        float mx[4], rs[4];
#pragma unroll
        for (int r = 0; r < 4; ++r)
            mx[r] = fmaxf(fmaxf(st[0][r], st[1][r]), fmaxf(st[2][r], st[3][r]));
#pragma unroll
        for (int offl = 1; offl < 16; offl <<= 1)
#pragma unroll
            for (int r = 0; r < 4; ++r) mx[r] = fmaxf(mx[r], __shfl_xor(mx[r], offl, 64));
        float fac[4];
#pragma unroll
        for (int r = 0; r < 4; ++r) {
            float nm = fmaxf(mrow[r], mx[r]);
            fac[r] = __expf(mrow[r] - nm);
            mrow[r] = nm;
            rs[r] = 0.f;
        }
#pragma unroll
        for (int kt = 0; kt < 4; ++kt) {
#pragma unroll
            for (int r = 0; r < 4; ++r) {
                float p = __expf(st[kt][r] - mrow[r]);
                rs[r] += p;
                Psm[(w * 16 + lg * 4 + r) * PP + kt * 16 + lr] = f2bf(p);
            }
        }
#pragma unroll
        for (int offl = 1; offl < 16; offl <<= 1)
#pragma unroll
            for (int r = 0; r < 4; ++r) rs[r] += __shfl_xor(rs[r], offl, 64);
#pragma unroll
        for (int r = 0; r < 4; ++r) lsum[r] = lsum[r] * fac[r] + rs[r];
#pragma unroll
        for (int dt = 0; dt < 4; ++dt)
#pragma unroll
            for (int r = 0; r < 4; ++r) o[dt][r] *= fac[r];

        // PV: A = P (row=q, k=key), B = Vt (n=d, k=key)
        __builtin_amdgcn_s_setprio(1);
#pragma unroll
        for (int ks = 0; ks < 2; ++ks) {
            short8 pa = *(const short8*)&Psm[(w * 16 + lr) * PP + ks * 32 + lg * 8];
#pragma unroll
            for (int dt = 0; dt < 4; ++dt) {
                short8 vf = swzread(Vc, dt * 16 + lr, ks * 64 + lg * 16);
                o[dt] = mfma16(pa, vf, o[dt]);
            }
        }
        __builtin_amdgcn_s_setprio(0);

        asm volatile("s_waitcnt vmcnt(0)" ::: "memory");
        __syncthreads();
    }
#undef STAGE

#pragma unroll
    for (int dt = 0; dt < 4; ++dt) {
#pragma unroll
        for (int r = 0; r < 4; ++r) {
            const int srow = q0 + w * 16 + lg * 4 + r;
            ob[headoff + (size_t)srow * DD + dt * 16 + lr] = f2bf(o[dt][r] / lsum[r]);
        }
    }
}

// ---------------- launch ----------------
extern "C" void kernel_launch(void* const* d_in, const int* in_sizes, int n_in,
                              void* d_out, int out_size, void* d_ws, size_t ws_size,
                              hipStream_t stream)
{
    (void)in_sizes; (void)n_in; (void)out_size; (void)ws_size;
    const float* x  = (const float*)d_in[0];
    const float* pc = (const float*)d_in[1];
    const float* ps = (const float*)d_in[2];
    const float* Wq = (const float*)d_in[3];
    const float* bq = (const float*)d_in[4];
    const float* Wk = (const float*)d_in[5];
    const float* bk = (const float*)d_in[6];
    const float* Wv = (const float*)d_in[7];
    const float* bv = (const float*)d_in[8];
    const float* qw = (const float*)d_in[9];
    const float* kw = (const float*)d_in[10];
    const float* Wo = (const float*)d_in[11];
    const float* bo = (const float*)d_in[12];
    float* out = (float*)d_out;

    const size_t MDsz = (size_t)MD * DD;
    const size_t DDsz = (size_t)DD * DD;
    u16* xb   = (u16*)d_ws;
    u16* wqb  = xb  + MDsz;
    u16* wkb  = wqb + DDsz;
    u16* wvb  = wkb + DDsz;
    u16* wob  = wvb + DDsz;
    u16* qbuf = wob + DDsz;
    u16* kbuf = qbuf + MDsz;
    u16* vbuf = kbuf + MDsz;
    u16* aob  = xb;            // attn output aliases xb (dead after QKV GEMM)
    u16* vtb  = wqb;           // V^T aliases wqb+wkb (dead after QKV GEMM, 16.8MB fits)

    const int n4m = (int)(MDsz / 4), n4d = (int)(DDsz / 4);
    cvt_f32_bf16<<<dim3((n4m + 255) / 256), 256, 0, stream>>>(x, xb, n4m);
    cvt_w4<<<dim3((n4d + 255) / 256, 4), 256, 0, stream>>>(
        Wq, Wk, Wv, Wo, wqb, wkb, wvb, wob, n4d);

    gemm_nt<0><<<dim3(DD / BN, MD / BM, 3), 256, 0, stream>>>(
        xb, wqb, wkb, wvb, bq, bk, bv,
        (void*)qbuf, (void*)kbuf, (void*)vbuf, MD, DD, DD);

    rmsnorm_rope<<<dim3(MD), 256, 0, stream>>>(qbuf, kbuf, qw, kw, pc, ps);
    transpose_v<<<dim3(SD / 64, BD * HD), 256, 0, stream>>>(vbuf, vtb);

    attn_fwd<<<dim3(SD / 64, BD * HD), 256, 0, stream>>>(qbuf, kbuf, vtb, aob);

    gemm_nt<1><<<dim3(DD / BN, MD / BM, 1), 256, 0, stream>>>(
        aob, wob, wob, wob, bo, bo, bo,
        (void*)out, (void*)out, (void*)out, MD, DD, DD);
}

// Round 3
// 404.180 us; speedup vs baseline: 1.3661x; 1.1473x over previous
//
#include <hip/hip_runtime.h>
#include <stdint.h>

// Problem constants (LTXSelfAttention: B=2, S=2048, D=2048, H=32, DH=64)
#define BD 2
#define SD 2048
#define DD 2048
#define HD 32
#define DH 64
#define MD (BD*SD)   // 4096 rows

typedef __attribute__((ext_vector_type(8))) short short8;
typedef __attribute__((ext_vector_type(8))) __bf16 bf16x8;
typedef __attribute__((ext_vector_type(4))) float f32x4;
typedef __attribute__((ext_vector_type(4))) unsigned int u32x4;
typedef unsigned short u16;
typedef unsigned int u32;

__device__ __forceinline__ u16 f2bf(float f) {
    u32 u = __float_as_uint(f);
    u32 r = (u + 0x7fffu + ((u >> 16) & 1u)) >> 16;   // RNE
    return (u16)r;
}
__device__ __forceinline__ u32 pk2(float a, float b) {
    return (u32)f2bf(a) | ((u32)f2bf(b) << 16);
}
__device__ __forceinline__ float bf2f(u16 h) {
    return __uint_as_float(((u32)h) << 16);
}
__device__ __forceinline__ f32x4 mfma16(short8 a, short8 b, f32x4 c) {
    return __builtin_amdgcn_mfma_f32_16x16x32_bf16(
        __builtin_bit_cast(bf16x8, a), __builtin_bit_cast(bf16x8, b), c, 0, 0, 0);
}
// async global->LDS, 16B per lane (wave-uniform LDS base + lane*16, linear dest)
__device__ __forceinline__ void gload16(const void* g, void* l) {
    __builtin_amdgcn_global_load_lds(
        (const __attribute__((address_space(1))) u32*)g,
        (__attribute__((address_space(3))) u32*)l, 16, 0, 0);
}

// ---------------- fp32 -> bf16 convert ----------------
__global__ __launch_bounds__(256) void cvt_f32_bf16(const float* __restrict__ s,
                                                    u16* __restrict__ d, int n4) {
    int i = blockIdx.x * 256 + threadIdx.x;
    if (i >= n4) return;
    float4 v = reinterpret_cast<const float4*>(s)[i];
    u32 lo = (u32)f2bf(v.x) | ((u32)f2bf(v.y) << 16);
    u32 hi = (u32)f2bf(v.z) | ((u32)f2bf(v.w) << 16);
    reinterpret_cast<uint2*>(d)[i] = make_uint2(lo, hi);
}
__global__ __launch_bounds__(256) void cvt_w4(
    const float* __restrict__ s0, const float* __restrict__ s1,
    const float* __restrict__ s2, const float* __restrict__ s3,
    u16* __restrict__ d0, u16* __restrict__ d1, u16* __restrict__ d2, u16* __restrict__ d3,
    int n4) {
    int i = blockIdx.x * 256 + threadIdx.x;
    if (i >= n4) return;
    int z = blockIdx.y;
    const float* s = z == 0 ? s0 : z == 1 ? s1 : z == 2 ? s2 : s3;
    u16* d = z == 0 ? d0 : z == 1 ? d1 : z == 2 ? d2 : d3;
    float4 v = reinterpret_cast<const float4*>(s)[i];
    u32 lo = (u32)f2bf(v.x) | ((u32)f2bf(v.y) << 16);
    u32 hi = (u32)f2bf(v.z) | ((u32)f2bf(v.w) << 16);
    reinterpret_cast<uint2*>(d)[i] = make_uint2(lo, hi);
}

// ---------------- GEMM: C[M,N] = A[M,K] * B[N,K]^T + bias (NT, bf16 in, fp32 acc) ----
#define BM 128
#define BN 128
#define BK 64

template<int OUTF32>
__global__ __launch_bounds__(256) void gemm_nt(
    const u16* __restrict__ A,
    const u16* __restrict__ B0, const u16* __restrict__ B1, const u16* __restrict__ B2,
    const float* __restrict__ c0, const float* __restrict__ c1, const float* __restrict__ c2,
    void* __restrict__ o0, void* __restrict__ o1, void* __restrict__ o2,
    int M, int N, int K)
{
    __shared__ __align__(16) u16 Asm[BM * BK];
    __shared__ __align__(16) u16 Bsm[BN * BK];
    const int z = blockIdx.z;
    const u16* Bm = z == 0 ? B0 : (z == 1 ? B1 : B2);
    const float* bias = z == 0 ? c0 : (z == 1 ? c1 : c2);
    void* outp = z == 0 ? o0 : (z == 1 ? o1 : o2);

    const int tid = threadIdx.x;
    const int m0 = blockIdx.y * BM;
    const int n0 = blockIdx.x * BN;
    const int lane = tid & 63;
    const int w = tid >> 6;
    const int wm = (w >> 1) * 64, wn = (w & 1) * 64;
    const int lr = lane & 15, lg = lane >> 4;

    const u16* aSrc = A + (size_t)(m0 + (tid >> 3)) * K + (tid & 7) * 8;
    const u16* bSrc = Bm + (size_t)(n0 + (tid >> 3)) * K + (tid & 7) * 8;
    u16* aDst = &Asm[tid * 8];
    u16* bDst = &Bsm[tid * 8];

    f32x4 acc[4][4];
#pragma unroll
    for (int i = 0; i < 4; ++i)
#pragma unroll
        for (int j = 0; j < 4; ++j) acc[i][j] = (f32x4){0.f, 0.f, 0.f, 0.f};

    for (int kt = 0; kt < K; kt += BK) {
        __syncthreads();
#pragma unroll
        for (int i = 0; i < 4; ++i) gload16(aSrc + (size_t)i * 32 * K + kt, aDst + i * 2048);
#pragma unroll
        for (int i = 0; i < 4; ++i) gload16(bSrc + (size_t)i * 32 * K + kt, bDst + i * 2048);
        asm volatile("s_waitcnt vmcnt(0)" ::: "memory");
        __syncthreads();
#pragma unroll
        for (int s = 0; s < 2; ++s) {
            const int kc = s * 32 + lg * 8;
            short8 av[4], bv[4];
#pragma unroll
            for (int i = 0; i < 4; ++i) av[i] = *(const short8*)&Asm[(wm + i * 16 + lr) * BK + kc];
#pragma unroll
            for (int j = 0; j < 4; ++j) bv[j] = *(const short8*)&Bsm[(wn + j * 16 + lr) * BK + kc];
#pragma unroll
            for (int i = 0; i < 4; ++i)
#pragma unroll
                for (int j = 0; j < 4; ++j) acc[i][j] = mfma16(av[i], bv[j], acc[i][j]);
        }
    }
#pragma unroll
    for (int j = 0; j < 4; ++j) {
        const int col = n0 + wn + j * 16 + lr;
        const float bj = bias[col];
#pragma unroll
        for (int i = 0; i < 4; ++i) {
            const int row = m0 + wm + i * 16 + lg * 4;
#pragma unroll
            for (int r = 0; r < 4; ++r) {
                float v = acc[i][j][r] + bj;
                if (OUTF32) ((float*)outp)[(size_t)(row + r) * N + col] = v;
                else        ((u16*)outp)[(size_t)(row + r) * N + col] = f2bf(v);
            }
        }
    }
}

// ---------------- fused RMSNorm + interleaved RoPE (q AND k per block) ------
__global__ __launch_bounds__(256) void rmsnorm_rope(
    u16* __restrict__ q, u16* __restrict__ k,
    const float* __restrict__ qw, const float* __restrict__ kw,
    const float* __restrict__ pc, const float* __restrict__ ps)
{
    const int row = blockIdx.x;           // 0..MD-1
    const int s = row & (SD - 1);
    const int off = threadIdx.x * 8;
    u16* qp = q + (size_t)row * DD + off;
    u16* kp = k + (size_t)row * DD + off;
    short8 qraw = *(const short8*)qp;
    short8 kraw = *(const short8*)kp;
    float vq[8], vk[8];
    float sq = 0.f, sk = 0.f;
#pragma unroll
    for (int j = 0; j < 8; ++j) {
        vq[j] = bf2f((u16)qraw[j]); sq += vq[j] * vq[j];
        vk[j] = bf2f((u16)kraw[j]); sk += vk[j] * vk[j];
    }
#pragma unroll
    for (int m = 1; m < 64; m <<= 1) { sq += __shfl_xor(sq, m, 64); sk += __shfl_xor(sk, m, 64); }
    __shared__ float redq[4], redk[4];
    const int w = threadIdx.x >> 6;
    if ((threadIdx.x & 63) == 0) { redq[w] = sq; redk[w] = sk; }
    __syncthreads();
    const float rq = rsqrtf((redq[0] + redq[1] + redq[2] + redq[3]) * (1.0f / DD) + 1e-6f);
    const float rk = rsqrtf((redk[0] + redk[1] + redk[2] + redk[3]) * (1.0f / DD) + 1e-6f);

    float wq[8], wk8[8], cv[8], sv[8];
    *(float4*)&wq[0]  = *(const float4*)(qw + off);
    *(float4*)&wq[4]  = *(const float4*)(qw + off + 4);
    *(float4*)&wk8[0] = *(const float4*)(kw + off);
    *(float4*)&wk8[4] = *(const float4*)(kw + off + 4);
    *(float4*)&cv[0] = *(const float4*)(pc + (size_t)s * DD + off);
    *(float4*)&cv[4] = *(const float4*)(pc + (size_t)s * DD + off + 4);
    *(float4*)&sv[0] = *(const float4*)(ps + (size_t)s * DD + off);
    *(float4*)&sv[4] = *(const float4*)(ps + (size_t)s * DD + off + 4);

    short8 qo, ko;
#pragma unroll
    for (int u = 0; u < 4; ++u) {
        float e  = vq[2 * u]     * rq * wq[2 * u];
        float od = vq[2 * u + 1] * rq * wq[2 * u + 1];
        qo[2 * u]     = (short)f2bf((e * cv[2 * u]      - od * sv[2 * u])     * 0.125f);
        qo[2 * u + 1] = (short)f2bf((od * cv[2 * u + 1] + e  * sv[2 * u + 1]) * 0.125f);
        e  = vk[2 * u]     * rk * wk8[2 * u];
        od = vk[2 * u + 1] * rk * wk8[2 * u + 1];
        ko[2 * u]     = (short)f2bf(e * cv[2 * u]      - od * sv[2 * u]);
        ko[2 * u + 1] = (short)f2bf(od * cv[2 * u + 1] + e  * sv[2 * u + 1]);
    }
    *(short8*)qp = qo;
    *(short8*)kp = ko;
}

// ---------------- V transpose: V[b,s,h*64+d] -> Vt[(b*32+h)*64+d][s] ----------------
__global__ __launch_bounds__(256) void transpose_v(
    const u16* __restrict__ v, u16* __restrict__ vt)
{
    __shared__ __align__(16) u16 t[64][80];
    const int bh = blockIdx.y;
    const int b = bh >> 5, h = bh & 31;
    const int s0 = blockIdx.x * 64;
    const int tid = threadIdx.x;
    const u16* src = v + (size_t)b * SD * DD + (size_t)h * DH;
#pragma unroll
    for (int i = 0; i < 2; ++i) {
        int c = tid + i * 256;
        int s = c >> 3, d8 = (c & 7) * 8;
        *(short8*)&t[s][d8] = *(const short8*)(src + (size_t)(s0 + s) * DD + d8);
    }
    __syncthreads();
    u16* dst = vt + (size_t)bh * DH * SD;
#pragma unroll
    for (int i = 0; i < 2; ++i) {
        int c = tid + i * 256;
        int d = c >> 3, s8 = (c & 7) * 8;
        short8 o;
#pragma unroll
        for (int j = 0; j < 8; ++j) o[j] = t[s8 + j][d];
        *(short8*)(dst + (size_t)d * SD + s0 + s8) = o;
    }
}

// ---------------- flash attention (swapped-QK^T, in-register P) ----------------
// block = 512 thr (8 waves), grid = (S/256, B*H). Wave: 32 q-rows (2 sub-tiles of 16).
// KV tile 64. K,Vt in XOR-swizzled LDS via global_load_lds, double-buffered.
// Swapped QK^T: st = mfma(K,Q) -> lane holds P[16 keys][its q]. Softmax per-lane +
// 2 shfl_xor. PV uses permuted key order pi(8g+j) so each lane's own P values form
// its A-fragment (zero cross-lane traffic); V read as 2x ds_read_b64 at matching keys.

__device__ __forceinline__ short8 swzread(const u16* base, int row, int colbyte) {
    return *(const short8*)((const char*)base + row * 128 + (colbyte ^ ((row & 7) << 4)));
}
__device__ __forceinline__ uint2 swz64(const u16* base, int row, int keyoff) {
    const int byteoff = keyoff * 2;
    const int addr = row * 128 + ((((byteoff >> 4) ^ (row & 7)) << 4) | (byteoff & 15));
    return *(const uint2*)((const char*)base + addr);
}

__global__ __launch_bounds__(512, 2) void attn_fwd(
    const u16* __restrict__ qb, const u16* __restrict__ kb,
    const u16* __restrict__ vt, u16* __restrict__ ob)
{
    __shared__ __align__(16) u16 Ksm[2][64 * 64];
    __shared__ __align__(16) u16 Vsm[2][64 * 64];
    const int bh = blockIdx.y;
    const int b = bh >> 5;
    const int q0 = blockIdx.x * 256;
    const int tid = threadIdx.x;
    const int w = tid >> 6, lane = tid & 63;
    const int lr = lane & 15, lg = lane >> 4;

    const size_t headoff = (size_t)b * SD * DD + (size_t)(bh & 31) * DH;
    const u16* kbase = kb + headoff;
    const u16* vtbase = vt + (size_t)bh * DH * SD;

    // Q fragments (used as MFMA B-operand: col=q=lane&15, k=(lane>>4)*8+j)
    const u16* qrow = qb + headoff + (size_t)(q0 + w * 32 + lr) * DD + lg * 8;
    short8 qf[2][2];
    qf[0][0] = *(const short8*)qrow;
    qf[0][1] = *(const short8*)(qrow + 32);
    qf[1][0] = *(const short8*)(qrow + 16 * DD);
    qf[1][1] = *(const short8*)(qrow + 16 * DD + 32);

    f32x4 o[2][4];
#pragma unroll
    for (int s = 0; s < 2; ++s)
#pragma unroll
        for (int dt = 0; dt < 4; ++dt) o[s][dt] = (f32x4){0.f, 0.f, 0.f, 0.f};
    float m_[2] = {-1e30f, -1e30f};
    float l_[2] = {0.f, 0.f};

    // staging: 512 chunks of 16B per tile-pair; chunk tid -> row rr, swizzled col cc
    const int rr = tid >> 3;
    const int cc = (tid & 7) ^ (rr & 7);

#define STAGE(buf, kv)                                                            \
    do {                                                                          \
        gload16(kbase + (size_t)((kv) + rr) * DD + cc * 8, &Ksm[buf][tid * 8]);   \
        gload16(vtbase + (size_t)rr * SD + (kv) + cc * 8, &Vsm[buf][tid * 8]);    \
    } while (0)

    STAGE(0, 0);
    asm volatile("s_waitcnt vmcnt(0)" ::: "memory");
    __syncthreads();

    for (int t = 0; t < SD / 64; ++t) {
        const int cur = t & 1;
        if (t + 1 < SD / 64) STAGE(cur ^ 1, (t + 1) * 64);

        const u16* Kc = Ksm[cur];
        const u16* Vc = Vsm[cur];

        // swapped scores: st[sub][kt], value = S[key=16kt+4lg+r][q=q0+w*32+sub*16+lr]
        f32x4 st[2][4];
        __builtin_amdgcn_s_setprio(1);
#pragma unroll
        for (int kt = 0; kt < 4; ++kt) {
            const int row = kt * 16 + lr;
            short8 kf0 = swzread(Kc, row, lg * 16);
            short8 kf1 = swzread(Kc, row, 64 + lg * 16);
            st[0][kt] = mfma16(kf1, qf[0][1], mfma16(kf0, qf[0][0], (f32x4){0.f, 0.f, 0.f, 0.f}));
            st[1][kt] = mfma16(kf1, qf[1][1], mfma16(kf0, qf[1][0], (f32x4){0.f, 0.f, 0.f, 0.f}));
        }
        __builtin_amdgcn_s_setprio(0);

        // softmax per sub: per-lane over 16 keys, cross-lane over 4 lane-groups
        u32x4 pa[2][2];
#pragma unroll
        for (int sub = 0; sub < 2; ++sub) {
            float mx = st[sub][0][0];
#pragma unroll
            for (int kt = 0; kt < 4; ++kt)
#pragma unroll
                for (int r = 0; r < 4; ++r) mx = fmaxf(mx, st[sub][kt][r]);
            mx = fmaxf(mx, __shfl_xor(mx, 16, 64));
            mx = fmaxf(mx, __shfl_xor(mx, 32, 64));
            const float mn = fmaxf(m_[sub], mx);
            const float fac = __expf(m_[sub] - mn);
            m_[sub] = mn;
            float p_[4][4];
            float rs = 0.f;
#pragma unroll
            for (int kt = 0; kt < 4; ++kt)
#pragma unroll
                for (int r = 0; r < 4; ++r) {
                    float pv = __expf(st[sub][kt][r] - mn);
                    p_[kt][r] = pv;
                    rs += pv;
                }
            rs += __shfl_xor(rs, 16, 64);
            rs += __shfl_xor(rs, 32, 64);
            l_[sub] = l_[sub] * fac + rs;
            // pack own keys into A-fragments (permuted key order)
#pragma unroll
            for (int ks = 0; ks < 2; ++ks) {
                u32x4 paw;
                paw[0] = pk2(p_[2 * ks][0], p_[2 * ks][1]);
                paw[1] = pk2(p_[2 * ks][2], p_[2 * ks][3]);
                paw[2] = pk2(p_[2 * ks + 1][0], p_[2 * ks + 1][1]);
                paw[3] = pk2(p_[2 * ks + 1][2], p_[2 * ks + 1][3]);
                pa[sub][ks] = paw;
            }
            // rescale O rows (o-row q = lg*4+r; fac lives at lane lr=q)
#pragma unroll
            for (int r = 0; r < 4; ++r) {
                const float fr = __shfl(fac, lg * 4 + r, 64);
#pragma unroll
                for (int dt = 0; dt < 4; ++dt) o[sub][dt][r] *= fr;
            }
        }

        // PV with permuted key order: vf element j = V[pi(8lg+j)+32ks][dt*16+lr]
        __builtin_amdgcn_s_setprio(1);
#pragma unroll
        for (int ks = 0; ks < 2; ++ks) {
#pragma unroll
            for (int dt = 0; dt < 4; ++dt) {
                const int d = dt * 16 + lr;
                uint2 vlo = swz64(Vc, d, ks * 32 + 4 * lg);
                uint2 vhi = swz64(Vc, d, ks * 32 + 16 + 4 * lg);
                u32x4 vw;
                vw[0] = vlo.x; vw[1] = vlo.y; vw[2] = vhi.x; vw[3] = vhi.y;
                short8 vf = __builtin_bit_cast(short8, vw);
                o[0][dt] = mfma16(__builtin_bit_cast(short8, pa[0][ks]), vf, o[0][dt]);
                o[1][dt] = mfma16(__builtin_bit_cast(short8, pa[1][ks]), vf, o[1][dt]);
            }
        }
        __builtin_amdgcn_s_setprio(0);

        asm volatile("s_waitcnt vmcnt(0)" ::: "memory");
        __syncthreads();
    }
#undef STAGE

    // epilogue: o[sub][dt][r] is O[q=q0+w*32+sub*16+lg*4+r][d=dt*16+lr]
#pragma unroll
    for (int sub = 0; sub < 2; ++sub) {
        const float li = 1.0f / l_[sub];
#pragma unroll
        for (int r = 0; r < 4; ++r) {
            const float lir = __shfl(li, lg * 4 + r, 64);
            const int srow = q0 + w * 32 + sub * 16 + lg * 4 + r;
#pragma unroll
            for (int dt = 0; dt < 4; ++dt)
                ob[headoff + (size_t)srow * DD + dt * 16 + lr] = f2bf(o[sub][dt][r] * lir);
        }
    }
}

// ---------------- launch ----------------
extern "C" void kernel_launch(void* const* d_in, const int* in_sizes, int n_in,
                              void* d_out, int out_size, void* d_ws, size_t ws_size,
                              hipStream_t stream)
{
    (void)in_sizes; (void)n_in; (void)out_size; (void)ws_size;
    const float* x  = (const float*)d_in[0];
    const float* pc = (const float*)d_in[1];
    const float* ps = (const float*)d_in[2];
    const float* Wq = (const float*)d_in[3];
    const float* bq = (const float*)d_in[4];
    const float* Wk = (const float*)d_in[5];
    const float* bk = (const float*)d_in[6];
    const float* Wv = (const float*)d_in[7];
    const float* bv = (const float*)d_in[8];
    const float* qw = (const float*)d_in[9];
    const float* kw = (const float*)d_in[10];
    const float* Wo = (const float*)d_in[11];
    const float* bo = (const float*)d_in[12];
    float* out = (float*)d_out;

    const size_t MDsz = (size_t)MD * DD;
    const size_t DDsz = (size_t)DD * DD;
    u16* xb   = (u16*)d_ws;
    u16* wqb  = xb  + MDsz;
    u16* wkb  = wqb + DDsz;
    u16* wvb  = wkb + DDsz;
    u16* wob  = wvb + DDsz;
    u16* qbuf = wob + DDsz;
    u16* kbuf = qbuf + MDsz;
    u16* vbuf = kbuf + MDsz;
    u16* aob  = xb;            // attn output aliases xb (dead after QKV GEMM)
    u16* vtb  = wqb;           // V^T aliases wqb+wkb (dead after QKV GEMM)

    const int n4m = (int)(MDsz / 4), n4d = (int)(DDsz / 4);
    cvt_f32_bf16<<<dim3((n4m + 255) / 256), 256, 0, stream>>>(x, xb, n4m);
    cvt_w4<<<dim3((n4d + 255) / 256, 4), 256, 0, stream>>>(
        Wq, Wk, Wv, Wo, wqb, wkb, wvb, wob, n4d);

    gemm_nt<0><<<dim3(DD / BN, MD / BM, 3), 256, 0, stream>>>(
        xb, wqb, wkb, wvb, bq, bk, bv,
        (void*)qbuf, (void*)kbuf, (void*)vbuf, MD, DD, DD);

    rmsnorm_rope<<<dim3(MD), 256, 0, stream>>>(qbuf, kbuf, qw, kw, pc, ps);
    transpose_v<<<dim3(SD / 64, BD * HD), 256, 0, stream>>>(vbuf, vtb);

    attn_fwd<<<dim3(SD / 256, BD * HD), 512, 0, stream>>>(qbuf, kbuf, vtb, aob);

    gemm_nt<1><<<dim3(DD / BN, MD / BM, 1), 256, 0, stream>>>(
        aob, wob, wob, wob, bo, bo, bo,
        (void*)out, (void*)out, (void*)out, MD, DD, DD);
}

// Round 4
// 343.603 us; speedup vs baseline: 1.6069x; 1.1763x over previous
//
#include <hip/hip_runtime.h>
#include <stdint.h>

// Problem constants (LTXSelfAttention: B=2, S=2048, D=2048, H=32, DH=64)
#define BD 2
#define SD 2048
#define DD 2048
#define HD 32
#define DH 64
#define MD (BD*SD)   // 4096 rows

typedef __attribute__((ext_vector_type(8))) short short8;
typedef __attribute__((ext_vector_type(8))) __bf16 bf16x8;
typedef __attribute__((ext_vector_type(4))) float f32x4;
typedef __attribute__((ext_vector_type(4))) unsigned int u32x4;
typedef unsigned short u16;
typedef unsigned int u32;

__device__ __forceinline__ u16 f2bf(float f) {
    u32 u = __float_as_uint(f);
    u32 r = (u + 0x7fffu + ((u >> 16) & 1u)) >> 16;   // RNE
    return (u16)r;
}
__device__ __forceinline__ u32 pk2(float a, float b) {
    return (u32)f2bf(a) | ((u32)f2bf(b) << 16);
}
__device__ __forceinline__ float bf2f(u16 h) {
    return __uint_as_float(((u32)h) << 16);
}
__device__ __forceinline__ f32x4 mfma16(short8 a, short8 b, f32x4 c) {
    return __builtin_amdgcn_mfma_f32_16x16x32_bf16(
        __builtin_bit_cast(bf16x8, a), __builtin_bit_cast(bf16x8, b), c, 0, 0, 0);
}
// async global->LDS, 16B per lane (wave-uniform LDS base + lane*16, linear dest)
__device__ __forceinline__ void gload16(const void* g, void* l) {
    __builtin_amdgcn_global_load_lds(
        (const __attribute__((address_space(1))) u32*)g,
        (__attribute__((address_space(3))) u32*)l, 16, 0, 0);
}
#if __has_builtin(__builtin_amdgcn_exp2f)
__device__ __forceinline__ float exp2x(float x) { return __builtin_amdgcn_exp2f(x); }
#else
__device__ __forceinline__ float exp2x(float x) { return exp2f(x); }
#endif

// 0.125 (1/sqrt(DH)) * log2(e): scores arrive in log2-domain -> softmax uses exp2
#define QSCALE 0.18033688011112042f

// ---------------- fp32 -> bf16 convert ----------------
__global__ __launch_bounds__(256) void cvt_f32_bf16(const float* __restrict__ s,
                                                    u16* __restrict__ d, int n4) {
    int i = blockIdx.x * 256 + threadIdx.x;
    if (i >= n4) return;
    float4 v = reinterpret_cast<const float4*>(s)[i];
    u32 lo = (u32)f2bf(v.x) | ((u32)f2bf(v.y) << 16);
    u32 hi = (u32)f2bf(v.z) | ((u32)f2bf(v.w) << 16);
    reinterpret_cast<uint2*>(d)[i] = make_uint2(lo, hi);
}
__global__ __launch_bounds__(256) void cvt_w4(
    const float* __restrict__ s0, const float* __restrict__ s1,
    const float* __restrict__ s2, const float* __restrict__ s3,
    u16* __restrict__ d0, u16* __restrict__ d1, u16* __restrict__ d2, u16* __restrict__ d3,
    int n4) {
    int i = blockIdx.x * 256 + threadIdx.x;
    if (i >= n4) return;
    int z = blockIdx.y;
    const float* s = z == 0 ? s0 : z == 1 ? s1 : z == 2 ? s2 : s3;
    u16* d = z == 0 ? d0 : z == 1 ? d1 : z == 2 ? d2 : d3;
    float4 v = reinterpret_cast<const float4*>(s)[i];
    u32 lo = (u32)f2bf(v.x) | ((u32)f2bf(v.y) << 16);
    u32 hi = (u32)f2bf(v.z) | ((u32)f2bf(v.w) << 16);
    reinterpret_cast<uint2*>(d)[i] = make_uint2(lo, hi);
}

// ---------------- GEMM v2: C[M,N] = A[M,K]*B[N,K]^T + bias ----------------
// 256x128 tile, BK=32, 512 threads (8 waves as 2Mx4N, 128x32 per wave).
// Double-buffered LDS (48KB), raw s_barrier + counted vmcnt(3) so prefetch
// loads stay in flight across barriers (T4). XOR-swizzle chunk^=(row>>1)&3
// keeps ds_read_b128 conflict-free. Prefetch t+2 issued AFTER the barrier
// that certifies all reads of that buffer completed.
template<int OUTF32>
__global__ __launch_bounds__(512, 4) void gemm_nt2(
    const u16* __restrict__ A,
    const u16* __restrict__ B0, const u16* __restrict__ B1, const u16* __restrict__ B2,
    const float* __restrict__ c0, const float* __restrict__ c1, const float* __restrict__ c2,
    void* __restrict__ o0, void* __restrict__ o1, void* __restrict__ o2,
    int M, int N, int K)
{
    __shared__ __align__(16) u16 As[2][256 * 32];
    __shared__ __align__(16) u16 Bs[2][128 * 32];
    const int z = blockIdx.z;
    const u16* Bm = z == 0 ? B0 : (z == 1 ? B1 : B2);
    const float* bias = z == 0 ? c0 : (z == 1 ? c1 : c2);
    void* outp = z == 0 ? o0 : (z == 1 ? o1 : o2);

    const int tid = threadIdx.x;
    const int m0 = blockIdx.y * 256;
    const int n0 = blockIdx.x * 128;
    const int lane = tid & 63, w = tid >> 6;
    const int wm = (w >> 2) * 128, wn = (w & 3) * 32;
    const int lr = lane & 15, lg = lane >> 4;

    // staging: chunk ch (16B) at LDS pos ch holds global col-chunk (ch&3)^((row>>1)&3)
    const int srow = tid >> 2;
    const int scol = ((tid & 3) ^ ((srow >> 1) & 3)) * 8;
    const u16* aS = A + (size_t)(m0 + srow) * K + scol;   // rows srow and srow+128
    const u16* bS = Bm + (size_t)(n0 + srow) * K + scol;

#define STG(buf, kt) do {                                                   \
    gload16(aS + (size_t)(kt) * 32, &As[buf][tid * 8]);                     \
    gload16(aS + (size_t)128 * K + (size_t)(kt) * 32, &As[buf][tid * 8 + 4096]); \
    gload16(bS + (size_t)(kt) * 32, &Bs[buf][tid * 8]); } while (0)

    f32x4 acc[8][2];
#pragma unroll
    for (int i = 0; i < 8; ++i) {
        acc[i][0] = (f32x4){0.f, 0.f, 0.f, 0.f};
        acc[i][1] = (f32x4){0.f, 0.f, 0.f, 0.f};
    }

    const int sa8 = (lg ^ ((lr >> 1) & 3)) * 8;   // swizzled chunk for frag reads

    STG(0, 0);
    STG(1, 1);
    asm volatile("s_waitcnt vmcnt(3)" ::: "memory");   // tile0 landed, tile1 in flight
    __builtin_amdgcn_s_barrier();
    __builtin_amdgcn_sched_barrier(0);

    const int KT = K / 32;   // 64
    for (int t = 0; t < KT; ++t) {
        const int cur = t & 1;
        const u16* aBase = &As[cur][(wm + lr) * 32 + sa8];
        const u16* bBase = &Bs[cur][(wn + lr) * 32 + sa8];
        short8 av[8], bv[2];
#pragma unroll
        for (int i = 0; i < 8; ++i) av[i] = *(const short8*)(aBase + i * 512);
        bv[0] = *(const short8*)bBase;
        bv[1] = *(const short8*)(bBase + 512);
        __builtin_amdgcn_s_setprio(1);
#pragma unroll
        for (int i = 0; i < 8; ++i) {
            acc[i][0] = mfma16(av[i], bv[0], acc[i][0]);
            acc[i][1] = mfma16(av[i], bv[1], acc[i][1]);
        }
        __builtin_amdgcn_s_setprio(0);
        asm volatile("s_waitcnt lgkmcnt(0)" ::: "memory");
        __builtin_amdgcn_sched_barrier(0);
        __builtin_amdgcn_s_barrier();              // all waves done reading buf[cur]
        __builtin_amdgcn_sched_barrier(0);
        if (t + 2 < KT) {
            STG(cur, t + 2);                       // overwrite buf[cur], now safe
            asm volatile("s_waitcnt vmcnt(3)" ::: "memory");   // tile t+1 landed
        } else {
            asm volatile("s_waitcnt vmcnt(0)" ::: "memory");
        }
        __builtin_amdgcn_sched_barrier(0);
        __builtin_amdgcn_s_barrier();              // buf[cur^1] visible to all
        __builtin_amdgcn_sched_barrier(0);
    }
#undef STG

    // epilogue: C/D layout col = lane&15, row = (lane>>4)*4 + reg
#pragma unroll
    for (int j = 0; j < 2; ++j) {
        const int col = n0 + wn + j * 16 + lr;
        const float bj = bias[col];
#pragma unroll
        for (int i = 0; i < 8; ++i) {
            const int row = m0 + wm + i * 16 + lg * 4;
#pragma unroll
            for (int r = 0; r < 4; ++r) {
                float v = acc[i][j][r] + bj;
                if (OUTF32) ((float*)outp)[(size_t)(row + r) * N + col] = v;
                else        ((u16*)outp)[(size_t)(row + r) * N + col] = f2bf(v);
            }
        }
    }
}

// ---------------- fused RMSNorm + interleaved RoPE (q AND k per block) ------
__global__ __launch_bounds__(256) void rmsnorm_rope(
    u16* __restrict__ q, u16* __restrict__ k,
    const float* __restrict__ qw, const float* __restrict__ kw,
    const float* __restrict__ pc, const float* __restrict__ ps)
{
    const int row = blockIdx.x;           // 0..MD-1
    const int s = row & (SD - 1);
    const int off = threadIdx.x * 8;
    u16* qp = q + (size_t)row * DD + off;
    u16* kp = k + (size_t)row * DD + off;
    short8 qraw = *(const short8*)qp;
    short8 kraw = *(const short8*)kp;
    float vq[8], vk[8];
    float sq = 0.f, sk = 0.f;
#pragma unroll
    for (int j = 0; j < 8; ++j) {
        vq[j] = bf2f((u16)qraw[j]); sq += vq[j] * vq[j];
        vk[j] = bf2f((u16)kraw[j]); sk += vk[j] * vk[j];
    }
#pragma unroll
    for (int m = 1; m < 64; m <<= 1) { sq += __shfl_xor(sq, m, 64); sk += __shfl_xor(sk, m, 64); }
    __shared__ float redq[4], redk[4];
    const int w = threadIdx.x >> 6;
    if ((threadIdx.x & 63) == 0) { redq[w] = sq; redk[w] = sk; }
    __syncthreads();
    const float rq = rsqrtf((redq[0] + redq[1] + redq[2] + redq[3]) * (1.0f / DD) + 1e-6f);
    const float rk = rsqrtf((redk[0] + redk[1] + redk[2] + redk[3]) * (1.0f / DD) + 1e-6f);

    float wq[8], wk8[8], cv[8], sv[8];
    *(float4*)&wq[0]  = *(const float4*)(qw + off);
    *(float4*)&wq[4]  = *(const float4*)(qw + off + 4);
    *(float4*)&wk8[0] = *(const float4*)(kw + off);
    *(float4*)&wk8[4] = *(const float4*)(kw + off + 4);
    *(float4*)&cv[0] = *(const float4*)(pc + (size_t)s * DD + off);
    *(float4*)&cv[4] = *(const float4*)(pc + (size_t)s * DD + off + 4);
    *(float4*)&sv[0] = *(const float4*)(ps + (size_t)s * DD + off);
    *(float4*)&sv[4] = *(const float4*)(ps + (size_t)s * DD + off + 4);

    short8 qo, ko;
#pragma unroll
    for (int u = 0; u < 4; ++u) {
        float e  = vq[2 * u]     * rq * wq[2 * u];
        float od = vq[2 * u + 1] * rq * wq[2 * u + 1];
        qo[2 * u]     = (short)f2bf((e * cv[2 * u]      - od * sv[2 * u])     * QSCALE);
        qo[2 * u + 1] = (short)f2bf((od * cv[2 * u + 1] + e  * sv[2 * u + 1]) * QSCALE);
        e  = vk[2 * u]     * rk * wk8[2 * u];
        od = vk[2 * u + 1] * rk * wk8[2 * u + 1];
        ko[2 * u]     = (short)f2bf(e * cv[2 * u]      - od * sv[2 * u]);
        ko[2 * u + 1] = (short)f2bf(od * cv[2 * u + 1] + e  * sv[2 * u + 1]);
    }
    *(short8*)qp = qo;
    *(short8*)kp = ko;
}

// ---------------- V transpose: V[b,s,h*64+d] -> Vt[(b*32+h)*64+d][s] ----------------
__global__ __launch_bounds__(256) void transpose_v(
    const u16* __restrict__ v, u16* __restrict__ vt)
{
    __shared__ __align__(16) u16 t[64][80];
    const int bh = blockIdx.y;
    const int b = bh >> 5, h = bh & 31;
    const int s0 = blockIdx.x * 64;
    const int tid = threadIdx.x;
    const u16* src = v + (size_t)b * SD * DD + (size_t)h * DH;
#pragma unroll
    for (int i = 0; i < 2; ++i) {
        int c = tid + i * 256;
        int s = c >> 3, d8 = (c & 7) * 8;
        *(short8*)&t[s][d8] = *(const short8*)(src + (size_t)(s0 + s) * DD + d8);
    }
    __syncthreads();
    u16* dst = vt + (size_t)bh * DH * SD;
#pragma unroll
    for (int i = 0; i < 2; ++i) {
        int c = tid + i * 256;
        int d = c >> 3, s8 = (c & 7) * 8;
        short8 o;
#pragma unroll
        for (int j = 0; j < 8; ++j) o[j] = t[s8 + j][d];
        *(short8*)(dst + (size_t)d * SD + s0 + s8) = o;
    }
}

// ---------------- flash attention (swapped-QK^T, in-register P, swapped PV) ----------
// block = 512 thr (8 waves), grid = (S/256, B*H). Wave: 32 q-rows (2 sub-tiles of 16).
// Scores in log2-domain (QSCALE folds log2e); defer-max (THR=8) skips rescale when
// __all(mx <= m+8). PV computes o = mfma(V, P): o's q lives on lane&15 like the
// softmax state -> rescale and epilogue are pure per-lane (zero shuffles).

__device__ __forceinline__ short8 swzread(const u16* base, int row, int colbyte) {
    return *(const short8*)((const char*)base + row * 128 + (colbyte ^ ((row & 7) << 4)));
}
__device__ __forceinline__ uint2 swz64(const u16* base, int row, int keyoff) {
    const int byteoff = keyoff * 2;
    const int addr = row * 128 + ((((byteoff >> 4) ^ (row & 7)) << 4) | (byteoff & 15));
    return *(const uint2*)((const char*)base + addr);
}

__global__ __launch_bounds__(512, 2) void attn_fwd(
    const u16* __restrict__ qb, const u16* __restrict__ kb,
    const u16* __restrict__ vt, u16* __restrict__ ob)
{
    __shared__ __align__(16) u16 Ksm[2][64 * 64];
    __shared__ __align__(16) u16 Vsm[2][64 * 64];
    const int bh = blockIdx.y;
    const int b = bh >> 5;
    const int q0 = blockIdx.x * 256;
    const int tid = threadIdx.x;
    const int w = tid >> 6, lane = tid & 63;
    const int lr = lane & 15, lg = lane >> 4;

    const size_t headoff = (size_t)b * SD * DD + (size_t)(bh & 31) * DH;
    const u16* kbase = kb + headoff;
    const u16* vtbase = vt + (size_t)bh * DH * SD;

    // Q fragments (MFMA B-operand: col=q=lane&15, k=(lane>>4)*8+j)
    const u16* qrow = qb + headoff + (size_t)(q0 + w * 32 + lr) * DD + lg * 8;
    short8 qf[2][2];
    qf[0][0] = *(const short8*)qrow;
    qf[0][1] = *(const short8*)(qrow + 32);
    qf[1][0] = *(const short8*)(qrow + 16 * DD);
    qf[1][1] = *(const short8*)(qrow + 16 * DD + 32);

    f32x4 o[2][4];
#pragma unroll
    for (int s = 0; s < 2; ++s)
#pragma unroll
        for (int dt = 0; dt < 4; ++dt) o[s][dt] = (f32x4){0.f, 0.f, 0.f, 0.f};
    float m_[2] = {-1e30f, -1e30f};
    float l_[2] = {0.f, 0.f};

    const int rr = tid >> 3;
    const int cc = (tid & 7) ^ (rr & 7);

#define STAGE(buf, kv)                                                            \
    do {                                                                          \
        gload16(kbase + (size_t)((kv) + rr) * DD + cc * 8, &Ksm[buf][tid * 8]);   \
        gload16(vtbase + (size_t)rr * SD + (kv) + cc * 8, &Vsm[buf][tid * 8]);    \
    } while (0)

    STAGE(0, 0);
    asm volatile("s_waitcnt vmcnt(0)" ::: "memory");
    __syncthreads();

    for (int t = 0; t < SD / 64; ++t) {
        const int cur = t & 1;
        if (t + 1 < SD / 64) STAGE(cur ^ 1, (t + 1) * 64);

        const u16* Kc = Ksm[cur];
        const u16* Vc = Vsm[cur];

        // swapped scores: st[sub][kt][r] = S[key=16kt+4lg+r][q=q0+w*32+sub*16+lr]
        f32x4 st[2][4];
        __builtin_amdgcn_s_setprio(1);
#pragma unroll
        for (int kt = 0; kt < 4; ++kt) {
            const int row = kt * 16 + lr;
            short8 kf0 = swzread(Kc, row, lg * 16);
            short8 kf1 = swzread(Kc, row, 64 + lg * 16);
            st[0][kt] = mfma16(kf1, qf[0][1], mfma16(kf0, qf[0][0], (f32x4){0.f, 0.f, 0.f, 0.f}));
            st[1][kt] = mfma16(kf1, qf[1][1], mfma16(kf0, qf[1][0], (f32x4){0.f, 0.f, 0.f, 0.f}));
        }
        __builtin_amdgcn_s_setprio(0);

        // softmax (log2 domain): per-lane over 16 keys + 2 shfl_xor over lane groups
        u32x4 pa[2][2];
#pragma unroll
        for (int sub = 0; sub < 2; ++sub) {
            float mx = st[sub][0][0];
#pragma unroll
            for (int kt = 0; kt < 4; ++kt)
#pragma unroll
                for (int r = 0; r < 4; ++r) mx = fmaxf(mx, st[sub][kt][r]);
            mx = fmaxf(mx, __shfl_xor(mx, 16, 64));
            mx = fmaxf(mx, __shfl_xor(mx, 32, 64));
            // defer-max (T13): only rescale when some q's max grew past threshold
            if (!__all(mx <= m_[sub] + 8.0f)) {
                const float mn = fmaxf(m_[sub], mx);
                const float fac = exp2x(m_[sub] - mn);
                m_[sub] = mn;
                l_[sub] *= fac;
#pragma unroll
                for (int dt = 0; dt < 4; ++dt)
#pragma unroll
                    for (int r = 0; r < 4; ++r) o[sub][dt][r] *= fac;
            }
            float p_[4][4];
            float rs = 0.f;
#pragma unroll
            for (int kt = 0; kt < 4; ++kt)
#pragma unroll
                for (int r = 0; r < 4; ++r) {
                    float pv = exp2x(st[sub][kt][r] - m_[sub]);
                    p_[kt][r] = pv;
                    rs += pv;
                }
            rs += __shfl_xor(rs, 16, 64);
            rs += __shfl_xor(rs, 32, 64);
            l_[sub] += rs;
            // pack own keys into B-operand frags, key order pi = ks*32+(j>>2)*16+lg*4+(j&3)
#pragma unroll
            for (int ks = 0; ks < 2; ++ks) {
                u32x4 paw;
                paw[0] = pk2(p_[2 * ks][0], p_[2 * ks][1]);
                paw[1] = pk2(p_[2 * ks][2], p_[2 * ks][3]);
                paw[2] = pk2(p_[2 * ks + 1][0], p_[2 * ks + 1][1]);
                paw[3] = pk2(p_[2 * ks + 1][2], p_[2 * ks + 1][3]);
                pa[sub][ks] = paw;
            }
        }

        // PV swapped: o = mfma(V, P). A=V^T[d][key pi], B=P[key pi][q]
        __builtin_amdgcn_s_setprio(1);
#pragma unroll
        for (int ks = 0; ks < 2; ++ks) {
#pragma unroll
            for (int dt = 0; dt < 4; ++dt) {
                const int d = dt * 16 + lr;
                uint2 vlo = swz64(Vc, d, ks * 32 + 4 * lg);
                uint2 vhi = swz64(Vc, d, ks * 32 + 16 + 4 * lg);
                u32x4 vw;
                vw[0] = vlo.x; vw[1] = vlo.y; vw[2] = vhi.x; vw[3] = vhi.y;
                short8 vf = __builtin_bit_cast(short8, vw);
                o[0][dt] = mfma16(vf, __builtin_bit_cast(short8, pa[0][ks]), o[0][dt]);
                o[1][dt] = mfma16(vf, __builtin_bit_cast(short8, pa[1][ks]), o[1][dt]);
            }
        }
        __builtin_amdgcn_s_setprio(0);

        asm volatile("s_waitcnt vmcnt(0)" ::: "memory");
        __syncthreads();
    }
#undef STAGE

    // epilogue: o[sub][dt][r] = O[q=q0+w*32+sub*16+lr][d=dt*16+lg*4+r] — per-lane
#pragma unroll
    for (int sub = 0; sub < 2; ++sub) {
        const float li = 1.0f / l_[sub];
        const int srow = q0 + w * 32 + sub * 16 + lr;
#pragma unroll
        for (int dt = 0; dt < 4; ++dt) {
            u32 w0 = pk2(o[sub][dt][0] * li, o[sub][dt][1] * li);
            u32 w1 = pk2(o[sub][dt][2] * li, o[sub][dt][3] * li);
            *(uint2*)(ob + headoff + (size_t)srow * DD + dt * 16 + lg * 4) = make_uint2(w0, w1);
        }
    }
}

// ---------------- launch ----------------
extern "C" void kernel_launch(void* const* d_in, const int* in_sizes, int n_in,
                              void* d_out, int out_size, void* d_ws, size_t ws_size,
                              hipStream_t stream)
{
    (void)in_sizes; (void)n_in; (void)out_size; (void)ws_size;
    const float* x  = (const float*)d_in[0];
    const float* pc = (const float*)d_in[1];
    const float* ps = (const float*)d_in[2];
    const float* Wq = (const float*)d_in[3];
    const float* bq = (const float*)d_in[4];
    const float* Wk = (const float*)d_in[5];
    const float* bk = (const float*)d_in[6];
    const float* Wv = (const float*)d_in[7];
    const float* bv = (const float*)d_in[8];
    const float* qw = (const float*)d_in[9];
    const float* kw = (const float*)d_in[10];
    const float* Wo = (const float*)d_in[11];
    const float* bo = (const float*)d_in[12];
    float* out = (float*)d_out;

    const size_t MDsz = (size_t)MD * DD;
    const size_t DDsz = (size_t)DD * DD;
    u16* xb   = (u16*)d_ws;
    u16* wqb  = xb  + MDsz;
    u16* wkb  = wqb + DDsz;
    u16* wvb  = wkb + DDsz;
    u16* wob  = wvb + DDsz;
    u16* qbuf = wob + DDsz;
    u16* kbuf = qbuf + MDsz;
    u16* vbuf = kbuf + MDsz;
    u16* aob  = xb;            // attn output aliases xb (dead after QKV GEMM)
    u16* vtb  = wqb;           // V^T aliases wqb+wkb (dead after QKV GEMM)

    const int n4m = (int)(MDsz / 4), n4d = (int)(DDsz / 4);
    cvt_f32_bf16<<<dim3((n4m + 255) / 256), 256, 0, stream>>>(x, xb, n4m);
    cvt_w4<<<dim3((n4d + 255) / 256, 4), 256, 0, stream>>>(
        Wq, Wk, Wv, Wo, wqb, wkb, wvb, wob, n4d);

    // QKV projections fused over grid.z; 256x128 tiles -> (16,16,3) = 768 blocks
    gemm_nt2<0><<<dim3(DD / 128, MD / 256, 3), 512, 0, stream>>>(
        xb, wqb, wkb, wvb, bq, bk, bv,
        (void*)qbuf, (void*)kbuf, (void*)vbuf, MD, DD, DD);

    rmsnorm_rope<<<dim3(MD), 256, 0, stream>>>(qbuf, kbuf, qw, kw, pc, ps);
    transpose_v<<<dim3(SD / 64, BD * HD), 256, 0, stream>>>(vbuf, vtb);

    attn_fwd<<<dim3(SD / 256, BD * HD), 512, 0, stream>>>(qbuf, kbuf, vtb, aob);

    gemm_nt2<1><<<dim3(DD / 128, MD / 256, 1), 512, 0, stream>>>(
        aob, wob, wob, wob, bo, bo, bo,
        (void*)out, (void*)out, (void*)out, MD, DD, DD);
}

// Round 5
// 296.344 us; speedup vs baseline: 1.8632x; 1.1595x over previous
//
#include <hip/hip_runtime.h>
#include <stdint.h>

// Problem constants (LTXSelfAttention: B=2, S=2048, D=2048, H=32, DH=64)
#define BD 2
#define SD 2048
#define DD 2048
#define HD 32
#define DH 64
#define MD (BD*SD)   // 4096 rows

typedef __attribute__((ext_vector_type(8))) short short8;
typedef __attribute__((ext_vector_type(8))) __bf16 bf16x8;
typedef __attribute__((ext_vector_type(4))) float f32x4;
typedef __attribute__((ext_vector_type(4))) unsigned int u32x4;
typedef unsigned short u16;
typedef unsigned int u32;

__device__ __forceinline__ u16 f2bf(float f) {
    u32 u = __float_as_uint(f);
    u32 r = (u + 0x7fffu + ((u >> 16) & 1u)) >> 16;   // RNE
    return (u16)r;
}
// packed f32x2 -> bf16x2 in one HW instr (D.lo = bf16(a), D.hi = bf16(b))
__device__ __forceinline__ u32 cvtpk(float a, float b) {
    u32 r;
    asm volatile("v_cvt_pk_bf16_f32 %0, %1, %2" : "=v"(r) : "v"(a), "v"(b));
    return r;
}
__device__ __forceinline__ float bf2f(u16 h) {
    return __uint_as_float(((u32)h) << 16);
}
__device__ __forceinline__ f32x4 mfma16(short8 a, short8 b, f32x4 c) {
    return __builtin_amdgcn_mfma_f32_16x16x32_bf16(
        __builtin_bit_cast(bf16x8, a), __builtin_bit_cast(bf16x8, b), c, 0, 0, 0);
}
// async global->LDS, 16B per lane (wave-uniform LDS base + lane*16, linear dest)
__device__ __forceinline__ void gload16(const void* g, void* l) {
    __builtin_amdgcn_global_load_lds(
        (const __attribute__((address_space(1))) u32*)g,
        (__attribute__((address_space(3))) u32*)l, 16, 0, 0);
}
#if __has_builtin(__builtin_amdgcn_exp2f)
__device__ __forceinline__ float exp2x(float x) { return __builtin_amdgcn_exp2f(x); }
#else
__device__ __forceinline__ float exp2x(float x) { return exp2f(x); }
#endif

// 0.125 (1/sqrt(DH)) * log2(e): scores arrive in log2-domain -> softmax uses exp2
#define QSCALE 0.18033688011112042f

// ---------------- fp32 -> bf16 convert ----------------
__global__ __launch_bounds__(256) void cvt_f32_bf16(const float* __restrict__ s,
                                                    u16* __restrict__ d, int n4) {
    int i = blockIdx.x * 256 + threadIdx.x;
    if (i >= n4) return;
    float4 v = reinterpret_cast<const float4*>(s)[i];
    reinterpret_cast<uint2*>(d)[i] = make_uint2(cvtpk(v.x, v.y), cvtpk(v.z, v.w));
}
__global__ __launch_bounds__(256) void cvt_w4(
    const float* __restrict__ s0, const float* __restrict__ s1,
    const float* __restrict__ s2, const float* __restrict__ s3,
    u16* __restrict__ d0, u16* __restrict__ d1, u16* __restrict__ d2, u16* __restrict__ d3,
    int n4) {
    int i = blockIdx.x * 256 + threadIdx.x;
    if (i >= n4) return;
    int z = blockIdx.y;
    const float* s = z == 0 ? s0 : z == 1 ? s1 : z == 2 ? s2 : s3;
    u16* d = z == 0 ? d0 : z == 1 ? d1 : z == 2 ? d2 : d3;
    float4 v = reinterpret_cast<const float4*>(s)[i];
    reinterpret_cast<uint2*>(d)[i] = make_uint2(cvtpk(v.x, v.y), cvtpk(v.z, v.w));
}

// ---------------- GEMM v3: C[M,N] = A[M,K]*B[N,K]^T + bias ----------------
// 256x128 tile, BK=32, 512 threads (8 waves as 2Mx4N, 128x32 per wave).
// THREE rotating LDS buffers (72KB, 2 blocks/CU), 2-deep prefetch, ONE barrier +
// counted vmcnt(3) per K-step (T4: tile t+1's loads stay in flight across the
// barrier and the whole compute phase). Buffer overwritten at iter t (slot t+2 mod 3
// == t-1 mod 3) was last read at iter t-1, one barrier ago -> race-free.
// XOR-swizzle chunk^=(row>>1)&3 keeps ds_read_b128 conflict-free (measured 0).
template<int OUTF32>
__global__ __launch_bounds__(512, 4) void gemm_nt3(
    const u16* __restrict__ A,
    const u16* __restrict__ B0, const u16* __restrict__ B1, const u16* __restrict__ B2,
    const float* __restrict__ c0, const float* __restrict__ c1, const float* __restrict__ c2,
    void* __restrict__ o0, void* __restrict__ o1, void* __restrict__ o2,
    int M, int N, int K)
{
    __shared__ __align__(16) u16 As[3][256 * 32];
    __shared__ __align__(16) u16 Bs[3][128 * 32];
    const int z = blockIdx.z;
    const u16* Bm = z == 0 ? B0 : (z == 1 ? B1 : B2);
    const float* bias = z == 0 ? c0 : (z == 1 ? c1 : c2);
    void* outp = z == 0 ? o0 : (z == 1 ? o1 : o2);

    const int tid = threadIdx.x;
    const int m0 = blockIdx.y * 256;
    const int n0 = blockIdx.x * 128;
    const int lane = tid & 63, w = tid >> 6;
    const int wm = (w >> 2) * 128, wn = (w & 3) * 32;
    const int lr = lane & 15, lg = lane >> 4;

    // staging: chunk at LDS pos (srow,c) holds global col-chunk c^((srow>>1)&3)
    const int srow = tid >> 2;
    const int scol = ((tid & 3) ^ ((srow >> 1) & 3)) * 8;
    const u16* aS = A + (size_t)(m0 + srow) * K + scol;   // rows srow and srow+128
    const u16* bS = Bm + (size_t)(n0 + srow) * K + scol;

#define STG(pa, pb, kt) do {                                                \
    gload16(aS + (size_t)(kt) * 32, (pa) + tid * 8);                        \
    gload16(aS + (size_t)128 * K + (size_t)(kt) * 32, (pa) + tid * 8 + 4096); \
    gload16(bS + (size_t)(kt) * 32, (pb) + tid * 8); } while (0)

    f32x4 acc[8][2];
#pragma unroll
    for (int i = 0; i < 8; ++i) {
        acc[i][0] = (f32x4){0.f, 0.f, 0.f, 0.f};
        acc[i][1] = (f32x4){0.f, 0.f, 0.f, 0.f};
    }

    const int sa8 = (lg ^ ((lr >> 1) & 3)) * 8;   // swizzled chunk for frag reads

    u16* a0 = As[0]; u16* a1 = As[1]; u16* a2 = As[2];
    u16* b0 = Bs[0]; u16* b1 = Bs[1]; u16* b2 = Bs[2];

    STG(a0, b0, 0);
    STG(a1, b1, 1);

    const int KT = K / 32;   // 64
    for (int t = 0; t < KT; ++t) {
        // tile t landed (3 loads of t+1 may stay in flight); all waves synced once
        if (t < KT - 1) asm volatile("s_waitcnt vmcnt(3)" ::: "memory");
        else            asm volatile("s_waitcnt vmcnt(0)" ::: "memory");
        __builtin_amdgcn_s_barrier();
        __builtin_amdgcn_sched_barrier(0);   // body must not float above the barrier

        const u16* aBase = a0 + (wm + lr) * 32 + sa8;
        const u16* bBase = b0 + (wn + lr) * 32 + sa8;
        short8 av[8], bv[2];
#pragma unroll
        for (int i = 0; i < 8; ++i) av[i] = *(const short8*)(aBase + i * 512);
        bv[0] = *(const short8*)bBase;
        bv[1] = *(const short8*)(bBase + 512);

        if (t + 2 < KT) STG(a2, b2, t + 2);   // overwrites slot last read at t-1

        __builtin_amdgcn_s_setprio(1);
#pragma unroll
        for (int i = 0; i < 8; ++i) {
            acc[i][0] = mfma16(av[i], bv[0], acc[i][0]);
            acc[i][1] = mfma16(av[i], bv[1], acc[i][1]);
        }
        __builtin_amdgcn_s_setprio(0);

        u16* ta = a0; a0 = a1; a1 = a2; a2 = ta;
        u16* tb = b0; b0 = b1; b1 = b2; b2 = tb;
    }
#undef STG

    // epilogue: C/D layout col = lane&15, row = (lane>>4)*4 + reg
#pragma unroll
    for (int j = 0; j < 2; ++j) {
        const int col = n0 + wn + j * 16 + lr;
        const float bj = bias[col];
#pragma unroll
        for (int i = 0; i < 8; ++i) {
            const int row = m0 + wm + i * 16 + lg * 4;
#pragma unroll
            for (int r = 0; r < 4; ++r) {
                float v = acc[i][j][r] + bj;
                if (OUTF32) ((float*)outp)[(size_t)(row + r) * N + col] = v;
                else        ((u16*)outp)[(size_t)(row + r) * N + col] = f2bf(v);
            }
        }
    }
}

// ---------------- fused RMSNorm + interleaved RoPE (q AND k per block) ------
__global__ __launch_bounds__(256) void rmsnorm_rope(
    u16* __restrict__ q, u16* __restrict__ k,
    const float* __restrict__ qw, const float* __restrict__ kw,
    const float* __restrict__ pc, const float* __restrict__ ps)
{
    const int row = blockIdx.x;           // 0..MD-1
    const int s = row & (SD - 1);
    const int off = threadIdx.x * 8;
    u16* qp = q + (size_t)row * DD + off;
    u16* kp = k + (size_t)row * DD + off;
    short8 qraw = *(const short8*)qp;
    short8 kraw = *(const short8*)kp;
    float vq[8], vk[8];
    float sq = 0.f, sk = 0.f;
#pragma unroll
    for (int j = 0; j < 8; ++j) {
        vq[j] = bf2f((u16)qraw[j]); sq += vq[j] * vq[j];
        vk[j] = bf2f((u16)kraw[j]); sk += vk[j] * vk[j];
    }
#pragma unroll
    for (int m = 1; m < 64; m <<= 1) { sq += __shfl_xor(sq, m, 64); sk += __shfl_xor(sk, m, 64); }
    __shared__ float redq[4], redk[4];
    const int w = threadIdx.x >> 6;
    if ((threadIdx.x & 63) == 0) { redq[w] = sq; redk[w] = sk; }
    __syncthreads();
    const float rq = rsqrtf((redq[0] + redq[1] + redq[2] + redq[3]) * (1.0f / DD) + 1e-6f);
    const float rk = rsqrtf((redk[0] + redk[1] + redk[2] + redk[3]) * (1.0f / DD) + 1e-6f);

    float wq[8], wk8[8], cv[8], sv[8];
    *(float4*)&wq[0]  = *(const float4*)(qw + off);
    *(float4*)&wq[4]  = *(const float4*)(qw + off + 4);
    *(float4*)&wk8[0] = *(const float4*)(kw + off);
    *(float4*)&wk8[4] = *(const float4*)(kw + off + 4);
    *(float4*)&cv[0] = *(const float4*)(pc + (size_t)s * DD + off);
    *(float4*)&cv[4] = *(const float4*)(pc + (size_t)s * DD + off + 4);
    *(float4*)&sv[0] = *(const float4*)(ps + (size_t)s * DD + off);
    *(float4*)&sv[4] = *(const float4*)(ps + (size_t)s * DD + off + 4);

    short8 qo, ko;
#pragma unroll
    for (int u = 0; u < 4; ++u) {
        float e  = vq[2 * u]     * rq * wq[2 * u];
        float od = vq[2 * u + 1] * rq * wq[2 * u + 1];
        qo[2 * u]     = (short)f2bf((e * cv[2 * u]      - od * sv[2 * u])     * QSCALE);
        qo[2 * u + 1] = (short)f2bf((od * cv[2 * u + 1] + e  * sv[2 * u + 1]) * QSCALE);
        e  = vk[2 * u]     * rk * wk8[2 * u];
        od = vk[2 * u + 1] * rk * wk8[2 * u + 1];
        ko[2 * u]     = (short)f2bf(e * cv[2 * u]      - od * sv[2 * u]);
        ko[2 * u + 1] = (short)f2bf(od * cv[2 * u + 1] + e  * sv[2 * u + 1]);
    }
    *(short8*)qp = qo;
    *(short8*)kp = ko;
}

// ---------------- V transpose: V[b,s,h*64+d] -> Vt[(b*32+h)*64+d][s] ----------------
__global__ __launch_bounds__(256) void transpose_v(
    const u16* __restrict__ v, u16* __restrict__ vt)
{
    __shared__ __align__(16) u16 t[64][80];
    const int bh = blockIdx.y;
    const int b = bh >> 5, h = bh & 31;
    const int s0 = blockIdx.x * 64;
    const int tid = threadIdx.x;
    const u16* src = v + (size_t)b * SD * DD + (size_t)h * DH;
#pragma unroll
    for (int i = 0; i < 2; ++i) {
        int c = tid + i * 256;
        int s = c >> 3, d8 = (c & 7) * 8;
        *(short8*)&t[s][d8] = *(const short8*)(src + (size_t)(s0 + s) * DD + d8);
    }
    __syncthreads();
    u16* dst = vt + (size_t)bh * DH * SD;
#pragma unroll
    for (int i = 0; i < 2; ++i) {
        int c = tid + i * 256;
        int d = c >> 3, s8 = (c & 7) * 8;
        short8 o;
#pragma unroll
        for (int j = 0; j < 8; ++j) o[j] = t[s8 + j][d];
        *(short8*)(dst + (size_t)d * SD + s0 + s8) = o;
    }
}

// ---------------- flash attention (swapped-QK^T, in-register P, swapped PV) ----------
// block = 512 thr (8 waves), grid = (S/256, B*H). Wave: 32 q-rows (2 sub-tiles of 16).
// Scores in log2-domain (QSCALE folds log2e); defer-max (THR=8) skips rescale when
// __all(mx <= m+8). PV computes o = mfma(V, P): o's q lives on lane&15 like the
// softmax state -> rescale and epilogue are pure per-lane. P packed via
// v_cvt_pk_bf16_f32 (1 instr per pair vs ~7 for hand-RNE).

__device__ __forceinline__ short8 swzread(const u16* base, int row, int colbyte) {
    return *(const short8*)((const char*)base + row * 128 + (colbyte ^ ((row & 7) << 4)));
}
__device__ __forceinline__ uint2 swz64(const u16* base, int row, int keyoff) {
    const int byteoff = keyoff * 2;
    const int addr = row * 128 + ((((byteoff >> 4) ^ (row & 7)) << 4) | (byteoff & 15));
    return *(const uint2*)((const char*)base + addr);
}

__global__ __launch_bounds__(512, 2) void attn_fwd(
    const u16* __restrict__ qb, const u16* __restrict__ kb,
    const u16* __restrict__ vt, u16* __restrict__ ob)
{
    __shared__ __align__(16) u16 Ksm[2][64 * 64];
    __shared__ __align__(16) u16 Vsm[2][64 * 64];
    const int bh = blockIdx.y;
    const int b = bh >> 5;
    const int q0 = blockIdx.x * 256;
    const int tid = threadIdx.x;
    const int w = tid >> 6, lane = tid & 63;
    const int lr = lane & 15, lg = lane >> 4;

    const size_t headoff = (size_t)b * SD * DD + (size_t)(bh & 31) * DH;
    const u16* kbase = kb + headoff;
    const u16* vtbase = vt + (size_t)bh * DH * SD;

    // Q fragments (MFMA B-operand: col=q=lane&15, k=(lane>>4)*8+j)
    const u16* qrow = qb + headoff + (size_t)(q0 + w * 32 + lr) * DD + lg * 8;
    short8 qf[2][2];
    qf[0][0] = *(const short8*)qrow;
    qf[0][1] = *(const short8*)(qrow + 32);
    qf[1][0] = *(const short8*)(qrow + 16 * DD);
    qf[1][1] = *(const short8*)(qrow + 16 * DD + 32);

    f32x4 o[2][4];
#pragma unroll
    for (int s = 0; s < 2; ++s)
#pragma unroll
        for (int dt = 0; dt < 4; ++dt) o[s][dt] = (f32x4){0.f, 0.f, 0.f, 0.f};
    float m_[2] = {-1e30f, -1e30f};
    float l_[2] = {0.f, 0.f};

    const int rr = tid >> 3;
    const int cc = (tid & 7) ^ (rr & 7);

#define STAGE(buf, kv)                                                            \
    do {                                                                          \
        gload16(kbase + (size_t)((kv) + rr) * DD + cc * 8, &Ksm[buf][tid * 8]);   \
        gload16(vtbase + (size_t)rr * SD + (kv) + cc * 8, &Vsm[buf][tid * 8]);    \
    } while (0)

    STAGE(0, 0);
    asm volatile("s_waitcnt vmcnt(0)" ::: "memory");
    __syncthreads();

    for (int t = 0; t < SD / 64; ++t) {
        const int cur = t & 1;
        if (t + 1 < SD / 64) STAGE(cur ^ 1, (t + 1) * 64);

        const u16* Kc = Ksm[cur];
        const u16* Vc = Vsm[cur];

        // swapped scores: st[sub][kt][r] = S[key=16kt+4lg+r][q=q0+w*32+sub*16+lr]
        f32x4 st[2][4];
        __builtin_amdgcn_s_setprio(1);
#pragma unroll
        for (int kt = 0; kt < 4; ++kt) {
            const int row = kt * 16 + lr;
            short8 kf0 = swzread(Kc, row, lg * 16);
            short8 kf1 = swzread(Kc, row, 64 + lg * 16);
            st[0][kt] = mfma16(kf1, qf[0][1], mfma16(kf0, qf[0][0], (f32x4){0.f, 0.f, 0.f, 0.f}));
            st[1][kt] = mfma16(kf1, qf[1][1], mfma16(kf0, qf[1][0], (f32x4){0.f, 0.f, 0.f, 0.f}));
        }
        __builtin_amdgcn_s_setprio(0);

        // softmax (log2 domain): per-lane over 16 keys + 2 shfl_xor over lane groups
        u32x4 pa[2][2];
#pragma unroll
        for (int sub = 0; sub < 2; ++sub) {
            float mx = st[sub][0][0];
#pragma unroll
            for (int kt = 0; kt < 4; ++kt)
#pragma unroll
                for (int r = 0; r < 4; ++r) mx = fmaxf(mx, st[sub][kt][r]);
            mx = fmaxf(mx, __shfl_xor(mx, 16, 64));
            mx = fmaxf(mx, __shfl_xor(mx, 32, 64));
            // defer-max (T13): only rescale when some q's max grew past threshold
            if (!__all(mx <= m_[sub] + 8.0f)) {
                const float mn = fmaxf(m_[sub], mx);
                const float fac = exp2x(m_[sub] - mn);
                m_[sub] = mn;
                l_[sub] *= fac;
#pragma unroll
                for (int dt = 0; dt < 4; ++dt)
#pragma unroll
                    for (int r = 0; r < 4; ++r) o[sub][dt][r] *= fac;
            }
            float p_[4][4];
            float rs = 0.f;
#pragma unroll
            for (int kt = 0; kt < 4; ++kt)
#pragma unroll
                for (int r = 0; r < 4; ++r) {
                    float pv = exp2x(st[sub][kt][r] - m_[sub]);
                    p_[kt][r] = pv;
                    rs += pv;
                }
            rs += __shfl_xor(rs, 16, 64);
            rs += __shfl_xor(rs, 32, 64);
            l_[sub] += rs;
            // pack own keys into B-operand frags, key order pi = ks*32+(j>>2)*16+lg*4+(j&3)
#pragma unroll
            for (int ks = 0; ks < 2; ++ks) {
                u32x4 paw;
                paw[0] = cvtpk(p_[2 * ks][0], p_[2 * ks][1]);
                paw[1] = cvtpk(p_[2 * ks][2], p_[2 * ks][3]);
                paw[2] = cvtpk(p_[2 * ks + 1][0], p_[2 * ks + 1][1]);
                paw[3] = cvtpk(p_[2 * ks + 1][2], p_[2 * ks + 1][3]);
                pa[sub][ks] = paw;
            }
        }

        // PV swapped: o = mfma(V, P). A=V^T[d][key pi], B=P[key pi][q]
        __builtin_amdgcn_s_setprio(1);
#pragma unroll
        for (int ks = 0; ks < 2; ++ks) {
#pragma unroll
            for (int dt = 0; dt < 4; ++dt) {
                const int d = dt * 16 + lr;
                uint2 vlo = swz64(Vc, d, ks * 32 + 4 * lg);
                uint2 vhi = swz64(Vc, d, ks * 32 + 16 + 4 * lg);
                u32x4 vw;
                vw[0] = vlo.x; vw[1] = vlo.y; vw[2] = vhi.x; vw[3] = vhi.y;
                short8 vf = __builtin_bit_cast(short8, vw);
                o[0][dt] = mfma16(vf, __builtin_bit_cast(short8, pa[0][ks]), o[0][dt]);
                o[1][dt] = mfma16(vf, __builtin_bit_cast(short8, pa[1][ks]), o[1][dt]);
            }
        }
        __builtin_amdgcn_s_setprio(0);

        asm volatile("s_waitcnt vmcnt(0)" ::: "memory");
        __syncthreads();
    }
#undef STAGE

    // epilogue: o[sub][dt][r] = O[q=q0+w*32+sub*16+lr][d=dt*16+lg*4+r] — per-lane
#pragma unroll
    for (int sub = 0; sub < 2; ++sub) {
        const float li = 1.0f / l_[sub];
        const int srow = q0 + w * 32 + sub * 16 + lr;
#pragma unroll
        for (int dt = 0; dt < 4; ++dt) {
            u32 w0 = cvtpk(o[sub][dt][0] * li, o[sub][dt][1] * li);
            u32 w1 = cvtpk(o[sub][dt][2] * li, o[sub][dt][3] * li);
            *(uint2*)(ob + headoff + (size_t)srow * DD + dt * 16 + lg * 4) = make_uint2(w0, w1);
        }
    }
}

// ---------------- launch ----------------
extern "C" void kernel_launch(void* const* d_in, const int* in_sizes, int n_in,
                              void* d_out, int out_size, void* d_ws, size_t ws_size,
                              hipStream_t stream)
{
    (void)in_sizes; (void)n_in; (void)out_size; (void)ws_size;
    const float* x  = (const float*)d_in[0];
    const float* pc = (const float*)d_in[1];
    const float* ps = (const float*)d_in[2];
    const float* Wq = (const float*)d_in[3];
    const float* bq = (const float*)d_in[4];
    const float* Wk = (const float*)d_in[5];
    const float* bk = (const float*)d_in[6];
    const float* Wv = (const float*)d_in[7];
    const float* bv = (const float*)d_in[8];
    const float* qw = (const float*)d_in[9];
    const float* kw = (const float*)d_in[10];
    const float* Wo = (const float*)d_in[11];
    const float* bo = (const float*)d_in[12];
    float* out = (float*)d_out;

    const size_t MDsz = (size_t)MD * DD;
    const size_t DDsz = (size_t)DD * DD;
    u16* xb   = (u16*)d_ws;
    u16* wqb  = xb  + MDsz;
    u16* wkb  = wqb + DDsz;
    u16* wvb  = wkb + DDsz;
    u16* wob  = wvb + DDsz;
    u16* qbuf = wob + DDsz;
    u16* kbuf = qbuf + MDsz;
    u16* vbuf = kbuf + MDsz;
    u16* aob  = xb;            // attn output aliases xb (dead after QKV GEMM)
    u16* vtb  = wqb;           // V^T aliases wqb+wkb (dead after QKV GEMM)

    const int n4m = (int)(MDsz / 4), n4d = (int)(DDsz / 4);
    cvt_f32_bf16<<<dim3((n4m + 255) / 256), 256, 0, stream>>>(x, xb, n4m);
    cvt_w4<<<dim3((n4d + 255) / 256, 4), 256, 0, stream>>>(
        Wq, Wk, Wv, Wo, wqb, wkb, wvb, wob, n4d);

    // QKV projections fused over grid.z; 256x128 tiles -> (16,16,3) = 768 blocks
    gemm_nt3<0><<<dim3(DD / 128, MD / 256, 3), 512, 0, stream>>>(
        xb, wqb, wkb, wvb, bq, bk, bv,
        (void*)qbuf, (void*)kbuf, (void*)vbuf, MD, DD, DD);

    rmsnorm_rope<<<dim3(MD), 256, 0, stream>>>(qbuf, kbuf, qw, kw, pc, ps);
    transpose_v<<<dim3(SD / 64, BD * HD), 256, 0, stream>>>(vbuf, vtb);

    attn_fwd<<<dim3(SD / 256, BD * HD), 512, 0, stream>>>(qbuf, kbuf, vtb, aob);

    gemm_nt3<1><<<dim3(DD / 128, MD / 256, 1), 512, 0, stream>>>(
        aob, wob, wob, wob, bo, bo, bo,
        (void*)out, (void*)out, (void*)out, MD, DD, DD);
}

// Round 6
// 294.083 us; speedup vs baseline: 1.8775x; 1.0077x over previous
//
#include <hip/hip_runtime.h>
#include <stdint.h>

// Problem constants (LTXSelfAttention: B=2, S=2048, D=2048, H=32, DH=64)
#define BD 2
#define SD 2048
#define DD 2048
#define HD 32
#define DH 64
#define MD (BD*SD)   // 4096 rows

typedef __attribute__((ext_vector_type(8))) short short8;
typedef __attribute__((ext_vector_type(8))) __bf16 bf16x8;
typedef __attribute__((ext_vector_type(4))) float f32x4;
typedef __attribute__((ext_vector_type(4))) unsigned int u32x4;
typedef unsigned short u16;
typedef unsigned int u32;

__device__ __forceinline__ u16 f2bf(float f) {
    u32 u = __float_as_uint(f);
    u32 r = (u + 0x7fffu + ((u >> 16) & 1u)) >> 16;   // RNE
    return (u16)r;
}
// packed f32x2 -> bf16x2 in one HW instr (D.lo = bf16(a), D.hi = bf16(b))
__device__ __forceinline__ u32 cvtpk(float a, float b) {
    u32 r;
    asm volatile("v_cvt_pk_bf16_f32 %0, %1, %2" : "=v"(r) : "v"(a), "v"(b));
    return r;
}
__device__ __forceinline__ float bf2f(u16 h) {
    return __uint_as_float(((u32)h) << 16);
}
__device__ __forceinline__ f32x4 mfma16(short8 a, short8 b, f32x4 c) {
    return __builtin_amdgcn_mfma_f32_16x16x32_bf16(
        __builtin_bit_cast(bf16x8, a), __builtin_bit_cast(bf16x8, b), c, 0, 0, 0);
}
// async global->LDS, 16B per lane (wave-uniform LDS base + lane*16, linear dest)
__device__ __forceinline__ void gload16(const void* g, void* l) {
    __builtin_amdgcn_global_load_lds(
        (const __attribute__((address_space(1))) u32*)g,
        (__attribute__((address_space(3))) u32*)l, 16, 0, 0);
}
#if __has_builtin(__builtin_amdgcn_exp2f)
__device__ __forceinline__ float exp2x(float x) { return __builtin_amdgcn_exp2f(x); }
#else
__device__ __forceinline__ float exp2x(float x) { return exp2f(x); }
#endif

// 0.125 (1/sqrt(DH)) * log2(e): scores arrive in log2-domain -> softmax uses exp2
#define QSCALE 0.18033688011112042f

// ---------------- fp32 -> bf16 convert ----------------
__global__ __launch_bounds__(256) void cvt_f32_bf16(const float* __restrict__ s,
                                                    u16* __restrict__ d, int n4) {
    int i = blockIdx.x * 256 + threadIdx.x;
    if (i >= n4) return;
    float4 v = reinterpret_cast<const float4*>(s)[i];
    reinterpret_cast<uint2*>(d)[i] = make_uint2(cvtpk(v.x, v.y), cvtpk(v.z, v.w));
}
__global__ __launch_bounds__(256) void cvt_w4(
    const float* __restrict__ s0, const float* __restrict__ s1,
    const float* __restrict__ s2, const float* __restrict__ s3,
    u16* __restrict__ d0, u16* __restrict__ d1, u16* __restrict__ d2, u16* __restrict__ d3,
    int n4) {
    int i = blockIdx.x * 256 + threadIdx.x;
    if (i >= n4) return;
    int z = blockIdx.y;
    const float* s = z == 0 ? s0 : z == 1 ? s1 : z == 2 ? s2 : s3;
    u16* d = z == 0 ? d0 : z == 1 ? d1 : z == 2 ? d2 : d3;
    float4 v = reinterpret_cast<const float4*>(s)[i];
    reinterpret_cast<uint2*>(d)[i] = make_uint2(cvtpk(v.x, v.y), cvtpk(v.z, v.w));
}

// ---------------- GEMM v4: C[M,N] = A[M,K]*B[N,K]^T + bias ----------------
// 256x128 tile, BK=32, 512 threads (8 waves as 4Mx2N, 64x64 per wave -> 8 b128
// frag reads per 16 MFMA, down from 10 in the 2Mx4N layout).
// THREE rotating LDS buffers (72KB, 2 blocks/CU), 2-deep prefetch, ONE barrier +
// counted vmcnt(3) per K-step (tile t+1's loads stay in flight across the barrier
// and the whole compute phase). Buffer overwritten at iter t was last read at
// iter t-1, one barrier ago -> race-free.
// XOR-swizzle chunk^=(row>>1)&3 keeps ds_read_b128 conflict-free (measured 0).
template<int OUTF32>
__global__ __launch_bounds__(512, 4) void gemm_nt4(
    const u16* __restrict__ A,
    const u16* __restrict__ B0, const u16* __restrict__ B1, const u16* __restrict__ B2,
    const float* __restrict__ c0, const float* __restrict__ c1, const float* __restrict__ c2,
    void* __restrict__ o0, void* __restrict__ o1, void* __restrict__ o2,
    int M, int N, int K)
{
    __shared__ __align__(16) u16 As[3][256 * 32];
    __shared__ __align__(16) u16 Bs[3][128 * 32];
    const int z = blockIdx.z;
    const u16* Bm = z == 0 ? B0 : (z == 1 ? B1 : B2);
    const float* bias = z == 0 ? c0 : (z == 1 ? c1 : c2);
    void* outp = z == 0 ? o0 : (z == 1 ? o1 : o2);

    const int tid = threadIdx.x;
    const int m0 = blockIdx.y * 256;
    const int n0 = blockIdx.x * 128;
    const int lane = tid & 63, w = tid >> 6;
    const int wm = (w >> 1) * 64, wn = (w & 1) * 64;   // 4M x 2N wave grid
    const int lr = lane & 15, lg = lane >> 4;

    // staging: chunk at LDS pos (srow,c) holds global col-chunk c^((srow>>1)&3)
    const int srow = tid >> 2;
    const int scol = ((tid & 3) ^ ((srow >> 1) & 3)) * 8;
    const u16* aS = A + (size_t)(m0 + srow) * K + scol;   // rows srow and srow+128
    const u16* bS = Bm + (size_t)(n0 + srow) * K + scol;

#define STG(pa, pb, kt) do {                                                \
    gload16(aS + (size_t)(kt) * 32, (pa) + tid * 8);                        \
    gload16(aS + (size_t)128 * K + (size_t)(kt) * 32, (pa) + tid * 8 + 4096); \
    gload16(bS + (size_t)(kt) * 32, (pb) + tid * 8); } while (0)

    f32x4 acc[4][4];
#pragma unroll
    for (int i = 0; i < 4; ++i)
#pragma unroll
        for (int j = 0; j < 4; ++j) acc[i][j] = (f32x4){0.f, 0.f, 0.f, 0.f};

    const int sa8 = (lg ^ ((lr >> 1) & 3)) * 8;   // swizzled chunk for frag reads

    u16* a0 = As[0]; u16* a1 = As[1]; u16* a2 = As[2];
    u16* b0 = Bs[0]; u16* b1 = Bs[1]; u16* b2 = Bs[2];

    STG(a0, b0, 0);
    STG(a1, b1, 1);

    const int KT = K / 32;   // 64
    for (int t = 0; t < KT; ++t) {
        // tile t landed (3 loads of t+1 may stay in flight); all waves synced once
        if (t < KT - 1) asm volatile("s_waitcnt vmcnt(3)" ::: "memory");
        else            asm volatile("s_waitcnt vmcnt(0)" ::: "memory");
        __builtin_amdgcn_s_barrier();
        __builtin_amdgcn_sched_barrier(0);   // body must not float above the barrier

        const u16* aBase = a0 + (wm + lr) * 32 + sa8;
        const u16* bBase = b0 + (wn + lr) * 32 + sa8;
        short8 av[4], bv[4];
#pragma unroll
        for (int i = 0; i < 4; ++i) av[i] = *(const short8*)(aBase + i * 512);
#pragma unroll
        for (int j = 0; j < 4; ++j) bv[j] = *(const short8*)(bBase + j * 512);

        if (t + 2 < KT) STG(a2, b2, t + 2);   // overwrites slot last read at t-1

        __builtin_amdgcn_s_setprio(1);
#pragma unroll
        for (int i = 0; i < 4; ++i)
#pragma unroll
            for (int j = 0; j < 4; ++j) acc[i][j] = mfma16(av[i], bv[j], acc[i][j]);
        __builtin_amdgcn_s_setprio(0);

        u16* ta = a0; a0 = a1; a1 = a2; a2 = ta;
        u16* tb = b0; b0 = b1; b1 = b2; b2 = tb;
    }
#undef STG

    // epilogue: C/D layout col = lane&15, row = (lane>>4)*4 + reg
#pragma unroll
    for (int j = 0; j < 4; ++j) {
        const int col = n0 + wn + j * 16 + lr;
        const float bj = bias[col];
#pragma unroll
        for (int i = 0; i < 4; ++i) {
            const int row = m0 + wm + i * 16 + lg * 4;
#pragma unroll
            for (int r = 0; r < 4; ++r) {
                float v = acc[i][j][r] + bj;
                if (OUTF32) ((float*)outp)[(size_t)(row + r) * N + col] = v;
                else        ((u16*)outp)[(size_t)(row + r) * N + col] = f2bf(v);
            }
        }
    }
}

// ---------------- fused RMSNorm + interleaved RoPE (q AND k per block) ------
__global__ __launch_bounds__(256) void rmsnorm_rope(
    u16* __restrict__ q, u16* __restrict__ k,
    const float* __restrict__ qw, const float* __restrict__ kw,
    const float* __restrict__ pc, const float* __restrict__ ps)
{
    const int row = blockIdx.x;           // 0..MD-1
    const int s = row & (SD - 1);
    const int off = threadIdx.x * 8;
    u16* qp = q + (size_t)row * DD + off;
    u16* kp = k + (size_t)row * DD + off;
    short8 qraw = *(const short8*)qp;
    short8 kraw = *(const short8*)kp;
    float vq[8], vk[8];
    float sq = 0.f, sk = 0.f;
#pragma unroll
    for (int j = 0; j < 8; ++j) {
        vq[j] = bf2f((u16)qraw[j]); sq += vq[j] * vq[j];
        vk[j] = bf2f((u16)kraw[j]); sk += vk[j] * vk[j];
    }
#pragma unroll
    for (int m = 1; m < 64; m <<= 1) { sq += __shfl_xor(sq, m, 64); sk += __shfl_xor(sk, m, 64); }
    __shared__ float redq[4], redk[4];
    const int w = threadIdx.x >> 6;
    if ((threadIdx.x & 63) == 0) { redq[w] = sq; redk[w] = sk; }
    __syncthreads();
    const float rq = rsqrtf((redq[0] + redq[1] + redq[2] + redq[3]) * (1.0f / DD) + 1e-6f);
    const float rk = rsqrtf((redk[0] + redk[1] + redk[2] + redk[3]) * (1.0f / DD) + 1e-6f);

    float wq[8], wk8[8], cv[8], sv[8];
    *(float4*)&wq[0]  = *(const float4*)(qw + off);
    *(float4*)&wq[4]  = *(const float4*)(qw + off + 4);
    *(float4*)&wk8[0] = *(const float4*)(kw + off);
    *(float4*)&wk8[4] = *(const float4*)(kw + off + 4);
    *(float4*)&cv[0] = *(const float4*)(pc + (size_t)s * DD + off);
    *(float4*)&cv[4] = *(const float4*)(pc + (size_t)s * DD + off + 4);
    *(float4*)&sv[0] = *(const float4*)(ps + (size_t)s * DD + off);
    *(float4*)&sv[4] = *(const float4*)(ps + (size_t)s * DD + off + 4);

    short8 qo, ko;
#pragma unroll
    for (int u = 0; u < 4; ++u) {
        float e  = vq[2 * u]     * rq * wq[2 * u];
        float od = vq[2 * u + 1] * rq * wq[2 * u + 1];
        qo[2 * u]     = (short)f2bf((e * cv[2 * u]      - od * sv[2 * u])     * QSCALE);
        qo[2 * u + 1] = (short)f2bf((od * cv[2 * u + 1] + e  * sv[2 * u + 1]) * QSCALE);
        e  = vk[2 * u]     * rk * wk8[2 * u];
        od = vk[2 * u + 1] * rk * wk8[2 * u + 1];
        ko[2 * u]     = (short)f2bf(e * cv[2 * u]      - od * sv[2 * u]);
        ko[2 * u + 1] = (short)f2bf(od * cv[2 * u + 1] + e  * sv[2 * u + 1]);
    }
    *(short8*)qp = qo;
    *(short8*)kp = ko;
}

// ---------------- V transpose: V[b,s,h*64+d] -> Vt[(b*32+h)*64+d][s] ----------------
__global__ __launch_bounds__(256) void transpose_v(
    const u16* __restrict__ v, u16* __restrict__ vt)
{
    __shared__ __align__(16) u16 t[64][80];
    const int bh = blockIdx.y;
    const int b = bh >> 5, h = bh & 31;
    const int s0 = blockIdx.x * 64;
    const int tid = threadIdx.x;
    const u16* src = v + (size_t)b * SD * DD + (size_t)h * DH;
#pragma unroll
    for (int i = 0; i < 2; ++i) {
        int c = tid + i * 256;
        int s = c >> 3, d8 = (c & 7) * 8;
        *(short8*)&t[s][d8] = *(const short8*)(src + (size_t)(s0 + s) * DD + d8);
    }
    __syncthreads();
    u16* dst = vt + (size_t)bh * DH * SD;
#pragma unroll
    for (int i = 0; i < 2; ++i) {
        int c = tid + i * 256;
        int d = c >> 3, s8 = (c & 7) * 8;
        short8 o;
#pragma unroll
        for (int j = 0; j < 8; ++j) o[j] = t[s8 + j][d];
        *(short8*)(dst + (size_t)d * SD + s0 + s8) = o;
    }
}

// ---------------- flash attention (swapped-QK^T, in-register P, swapped PV) ----------
// block = 512 thr (8 waves), grid = (S/256, B*H). Wave: 32 q-rows (2 sub-tiles of 16).
// Scores in log2-domain (QSCALE folds log2e); defer-max (THR=8) skips rescale when
// __all(mx <= m+8). PV computes o = mfma(V, P): o's q lives on lane&15 like the
// softmax state -> rescale and epilogue are pure per-lane. P packed via
// v_cvt_pk_bf16_f32 (1 instr per pair vs ~7 for hand-RNE).

__device__ __forceinline__ short8 swzread(const u16* base, int row, int colbyte) {
    return *(const short8*)((const char*)base + row * 128 + (colbyte ^ ((row & 7) << 4)));
}
__device__ __forceinline__ uint2 swz64(const u16* base, int row, int keyoff) {
    const int byteoff = keyoff * 2;
    const int addr = row * 128 + ((((byteoff >> 4) ^ (row & 7)) << 4) | (byteoff & 15));
    return *(const uint2*)((const char*)base + addr);
}

__global__ __launch_bounds__(512, 2) void attn_fwd(
    const u16* __restrict__ qb, const u16* __restrict__ kb,
    const u16* __restrict__ vt, u16* __restrict__ ob)
{
    __shared__ __align__(16) u16 Ksm[2][64 * 64];
    __shared__ __align__(16) u16 Vsm[2][64 * 64];
    const int bh = blockIdx.y;
    const int b = bh >> 5;
    const int q0 = blockIdx.x * 256;
    const int tid = threadIdx.x;
    const int w = tid >> 6, lane = tid & 63;
    const int lr = lane & 15, lg = lane >> 4;

    const size_t headoff = (size_t)b * SD * DD + (size_t)(bh & 31) * DH;
    const u16* kbase = kb + headoff;
    const u16* vtbase = vt + (size_t)bh * DH * SD;

    // Q fragments (MFMA B-operand: col=q=lane&15, k=(lane>>4)*8+j)
    const u16* qrow = qb + headoff + (size_t)(q0 + w * 32 + lr) * DD + lg * 8;
    short8 qf[2][2];
    qf[0][0] = *(const short8*)qrow;
    qf[0][1] = *(const short8*)(qrow + 32);
    qf[1][0] = *(const short8*)(qrow + 16 * DD);
    qf[1][1] = *(const short8*)(qrow + 16 * DD + 32);

    f32x4 o[2][4];
#pragma unroll
    for (int s = 0; s < 2; ++s)
#pragma unroll
        for (int dt = 0; dt < 4; ++dt) o[s][dt] = (f32x4){0.f, 0.f, 0.f, 0.f};
    float m_[2] = {-1e30f, -1e30f};
    float l_[2] = {0.f, 0.f};

    const int rr = tid >> 3;
    const int cc = (tid & 7) ^ (rr & 7);

#define STAGE(buf, kv)                                                            \
    do {                                                                          \
        gload16(kbase + (size_t)((kv) + rr) * DD + cc * 8, &Ksm[buf][tid * 8]);   \
        gload16(vtbase + (size_t)rr * SD + (kv) + cc * 8, &Vsm[buf][tid * 8]);    \
    } while (0)

    STAGE(0, 0);
    asm volatile("s_waitcnt vmcnt(0)" ::: "memory");
    __syncthreads();

    for (int t = 0; t < SD / 64; ++t) {
        const int cur = t & 1;
        if (t + 1 < SD / 64) STAGE(cur ^ 1, (t + 1) * 64);

        const u16* Kc = Ksm[cur];
        const u16* Vc = Vsm[cur];

        // swapped scores: st[sub][kt][r] = S[key=16kt+4lg+r][q=q0+w*32+sub*16+lr]
        f32x4 st[2][4];
        __builtin_amdgcn_s_setprio(1);
#pragma unroll
        for (int kt = 0; kt < 4; ++kt) {
            const int row = kt * 16 + lr;
            short8 kf0 = swzread(Kc, row, lg * 16);
            short8 kf1 = swzread(Kc, row, 64 + lg * 16);
            st[0][kt] = mfma16(kf1, qf[0][1], mfma16(kf0, qf[0][0], (f32x4){0.f, 0.f, 0.f, 0.f}));
            st[1][kt] = mfma16(kf1, qf[1][1], mfma16(kf0, qf[1][0], (f32x4){0.f, 0.f, 0.f, 0.f}));
        }
        __builtin_amdgcn_s_setprio(0);

        // softmax (log2 domain): per-lane over 16 keys + 2 shfl_xor over lane groups
        u32x4 pa[2][2];
#pragma unroll
        for (int sub = 0; sub < 2; ++sub) {
            float mx = st[sub][0][0];
#pragma unroll
            for (int kt = 0; kt < 4; ++kt)
#pragma unroll
                for (int r = 0; r < 4; ++r) mx = fmaxf(mx, st[sub][kt][r]);
            mx = fmaxf(mx, __shfl_xor(mx, 16, 64));
            mx = fmaxf(mx, __shfl_xor(mx, 32, 64));
            // defer-max (T13): only rescale when some q's max grew past threshold
            if (!__all(mx <= m_[sub] + 8.0f)) {
                const float mn = fmaxf(m_[sub], mx);
                const float fac = exp2x(m_[sub] - mn);
                m_[sub] = mn;
                l_[sub] *= fac;
#pragma unroll
                for (int dt = 0; dt < 4; ++dt)
#pragma unroll
                    for (int r = 0; r < 4; ++r) o[sub][dt][r] *= fac;
            }
            float p_[4][4];
            float rs = 0.f;
#pragma unroll
            for (int kt = 0; kt < 4; ++kt)
#pragma unroll
                for (int r = 0; r < 4; ++r) {
                    float pv = exp2x(st[sub][kt][r] - m_[sub]);
                    p_[kt][r] = pv;
                    rs += pv;
                }
            rs += __shfl_xor(rs, 16, 64);
            rs += __shfl_xor(rs, 32, 64);
            l_[sub] += rs;
            // pack own keys into B-operand frags, key order pi = ks*32+(j>>2)*16+lg*4+(j&3)
#pragma unroll
            for (int ks = 0; ks < 2; ++ks) {
                u32x4 paw;
                paw[0] = cvtpk(p_[2 * ks][0], p_[2 * ks][1]);
                paw[1] = cvtpk(p_[2 * ks][2], p_[2 * ks][3]);
                paw[2] = cvtpk(p_[2 * ks + 1][0], p_[2 * ks + 1][1]);
                paw[3] = cvtpk(p_[2 * ks + 1][2], p_[2 * ks + 1][3]);
                pa[sub][ks] = paw;
            }
        }

        // PV swapped: o = mfma(V, P). A=V^T[d][key pi], B=P[key pi][q]
        __builtin_amdgcn_s_setprio(1);
#pragma unroll
        for (int ks = 0; ks < 2; ++ks) {
#pragma unroll
            for (int dt = 0; dt < 4; ++dt) {
                const int d = dt * 16 + lr;
                uint2 vlo = swz64(Vc, d, ks * 32 + 4 * lg);
                uint2 vhi = swz64(Vc, d, ks * 32 + 16 + 4 * lg);
                u32x4 vw;
                vw[0] = vlo.x; vw[1] = vlo.y; vw[2] = vhi.x; vw[3] = vhi.y;
                short8 vf = __builtin_bit_cast(short8, vw);
                o[0][dt] = mfma16(vf, __builtin_bit_cast(short8, pa[0][ks]), o[0][dt]);
                o[1][dt] = mfma16(vf, __builtin_bit_cast(short8, pa[1][ks]), o[1][dt]);
            }
        }
        __builtin_amdgcn_s_setprio(0);

        asm volatile("s_waitcnt vmcnt(0)" ::: "memory");
        __syncthreads();
    }
#undef STAGE

    // epilogue: o[sub][dt][r] = O[q=q0+w*32+sub*16+lr][d=dt*16+lg*4+r] — per-lane
#pragma unroll
    for (int sub = 0; sub < 2; ++sub) {
        const float li = 1.0f / l_[sub];
        const int srow = q0 + w * 32 + sub * 16 + lr;
#pragma unroll
        for (int dt = 0; dt < 4; ++dt) {
            u32 w0 = cvtpk(o[sub][dt][0] * li, o[sub][dt][1] * li);
            u32 w1 = cvtpk(o[sub][dt][2] * li, o[sub][dt][3] * li);
            *(uint2*)(ob + headoff + (size_t)srow * DD + dt * 16 + lg * 4) = make_uint2(w0, w1);
        }
    }
}

// ---------------- launch ----------------
extern "C" void kernel_launch(void* const* d_in, const int* in_sizes, int n_in,
                              void* d_out, int out_size, void* d_ws, size_t ws_size,
                              hipStream_t stream)
{
    (void)in_sizes; (void)n_in; (void)out_size; (void)ws_size;
    const float* x  = (const float*)d_in[0];
    const float* pc = (const float*)d_in[1];
    const float* ps = (const float*)d_in[2];
    const float* Wq = (const float*)d_in[3];
    const float* bq = (const float*)d_in[4];
    const float* Wk = (const float*)d_in[5];
    const float* bk = (const float*)d_in[6];
    const float* Wv = (const float*)d_in[7];
    const float* bv = (const float*)d_in[8];
    const float* qw = (const float*)d_in[9];
    const float* kw = (const float*)d_in[10];
    const float* Wo = (const float*)d_in[11];
    const float* bo = (const float*)d_in[12];
    float* out = (float*)d_out;

    const size_t MDsz = (size_t)MD * DD;
    const size_t DDsz = (size_t)DD * DD;
    u16* xb   = (u16*)d_ws;
    u16* wqb  = xb  + MDsz;
    u16* wkb  = wqb + DDsz;
    u16* wvb  = wkb + DDsz;
    u16* wob  = wvb + DDsz;
    u16* qbuf = wob + DDsz;
    u16* kbuf = qbuf + MDsz;
    u16* vbuf = kbuf + MDsz;
    u16* aob  = xb;            // attn output aliases xb (dead after QKV GEMM)
    u16* vtb  = wqb;           // V^T aliases wqb+wkb (dead after QKV GEMM)

    const int n4m = (int)(MDsz / 4), n4d = (int)(DDsz / 4);
    cvt_f32_bf16<<<dim3((n4m + 255) / 256), 256, 0, stream>>>(x, xb, n4m);
    cvt_w4<<<dim3((n4d + 255) / 256, 4), 256, 0, stream>>>(
        Wq, Wk, Wv, Wo, wqb, wkb, wvb, wob, n4d);

    // QKV projections fused over grid.z; 256x128 tiles -> (16,16,3) = 768 blocks
    gemm_nt4<0><<<dim3(DD / 128, MD / 256, 3), 512, 0, stream>>>(
        xb, wqb, wkb, wvb, bq, bk, bv,
        (void*)qbuf, (void*)kbuf, (void*)vbuf, MD, DD, DD);

    rmsnorm_rope<<<dim3(MD), 256, 0, stream>>>(qbuf, kbuf, qw, kw, pc, ps);
    transpose_v<<<dim3(SD / 64, BD * HD), 256, 0, stream>>>(vbuf, vtb);

    attn_fwd<<<dim3(SD / 256, BD * HD), 512, 0, stream>>>(qbuf, kbuf, vtb, aob);

    gemm_nt4<1><<<dim3(DD / 128, MD / 256, 1), 512, 0, stream>>>(
        aob, wob, wob, wob, bo, bo, bo,
        (void*)out, (void*)out, (void*)out, MD, DD, DD);
}